// Round 8
// baseline (2120.981 us; speedup 1.0000x reference)
//
#include <hip/hip_runtime.h>

#define B_ 2
#define L_ 3584
#define E_ 820
#define H_ 20
#define D_ 41
#define CB_ 7
#define LC_ 512      // L_/CB_
#define TOPK_ 16
#define NSEL_ 112    // TOPK_*CB_
#define QB_ 112      // L_/32 query-blocks per head
#define NREP_ 4      // fp64 score replicas (fallback path)
#define SCALE 0.15617376188860607f  // 1/sqrt(41)

typedef unsigned short bfu;
typedef __attribute__((ext_vector_type(8))) short bf16x8;   // 8 bf16 (4 VGPRs)
typedef __attribute__((ext_vector_type(4))) float f32x4;    // MFMA C/D

__device__ __forceinline__ float b2f(bfu h) {
    union { unsigned u; float f; } c; c.u = ((unsigned)h) << 16; return c.f;
}
__device__ __forceinline__ bfu f2b(float f) {
    union { float f; unsigned u; } c; c.f = f;
    unsigned u = c.u;
    return (bfu)((u + 0x7fffu + ((u >> 16) & 1u)) >> 16);
}
__device__ __forceinline__ void b2x2(unsigned u, float& a, float& b) {
    union { unsigned u; float f; } c0, c1;
    c0.u = u << 16; c1.u = u & 0xffff0000u;
    a = c0.f; b = c1.f;
}

// ---------------- workspace layout (bytes) — per-batch reuse ----------------
#define NHLD ((size_t)H_ * L_ * D_)
#define OFF_R1   ((size_t)0)                          // fp32 (k32 then q32)
#define OFF_V32  (OFF_R1  + NHLD * 4)                 // fp32 V
#define OFF_K16  (OFF_V32 + NHLD * 4)                 // bf16 K
#define OFF_KCT  (OFF_K16 + NHLD * 2)                 // fp32 kc^T [H][44][512]
#define OFF_VCF  (OFF_KCT + (size_t)H_ * 44 * LC_ * 4)   // bf16 vc frag [H][16][3][64][8]
#define OFF_BS   (OFF_VCF + (size_t)H_ * 16 * 3 * 64 * 8 * 2)  // fp64 x NREP_ (fallback)
#define OFF_IDX  (OFF_BS  + (size_t)NREP_ * H_ * LC_ * 8)
#define WS_NEEDED (OFF_IDX + (size_t)H_ * TOPK_ * 4)  // 32,503,040 <= proven 32,830,720
// optional extension: per-block fp32 block-score partials [H][QB_][LC_]
#define OFF_BSP  WS_NEEDED
#define WS_BIG   (OFF_BSP + (size_t)H_ * QB_ * LC_ * 4)

// ================= K-fail =================
__global__ __launch_bounds__(256) void k_fail(float* __restrict__ out, int n) {
    int i = blockIdx.x * 256 + threadIdx.x;
    if (i < n) out[i] = 0.f;
}

// ================= K0: zero block scores (double, atomic-fallback mode only) ==
__global__ __launch_bounds__(256) void k_zero_d(double* __restrict__ p, int n) {
    int i = blockIdx.x * 256 + threadIdx.x;
    if (i < n) p[i] = 0.0;
}

// ================= K1 v7: projection, NO LDS, symmetric 2-deep x+w pipeline =====
// grid (L_/ROWS, 2, nz), block 256. ROWS rows x 512 cols per block, 2 cols/thread.
// x loads are wave-uniform (scalar path); BOTH x and w are double-buffered with
// reload-into-freed-buffer (no copies): group g's buffers are refilled for g+2
// right after g's FMAs, giving >= 1 full group of latency cover. Bit-identical
// to v6 (per-acc FMA order e=0..819 ascending, 4 at a time).
template<int ROWS>
__global__ __launch_bounds__(256, 4) void k_proj2t(
    const float* __restrict__ x,
    const float* __restrict__ wA, const float* __restrict__ bA, float* __restrict__ outA,
    const float* __restrict__ wB, const float* __restrict__ bB, float* __restrict__ outB,
    int b)
{
    const float* w    = (blockIdx.z == 0) ? wA : wB;
    const float* bias = (blockIdx.z == 0) ? bA : bB;
    float* outp       = (blockIdx.z == 0) ? outA : outB;
    const int row0 = blockIdx.x * ROWS;
    const int c0 = blockIdx.y * 512 + threadIdx.x;   // always < 820
    const int c1 = c0 + 256;
    const bool a1 = (c1 < E_);
    const int cc1 = a1 ? c1 : (E_ - 1);
    float acc0[ROWS], acc1[ROWS];
    const float bb0 = bias[c0];
    const float bb1 = bias[cc1];
#pragma unroll
    for (int r = 0; r < ROWS; r++) { acc0[r] = bb0; acc1[r] = bb1; }

    const float* xp  = x + ((size_t)b * L_ + row0) * E_;  // uniform row-block base
    const float* wp0 = w + c0;
    const float* wp1 = w + cc1;

#define PG_LOADX(XB, G)                                          \
    _Pragma("unroll")                                            \
    for (int r = 0; r < ROWS; r++)                               \
        XB[r] = *(const float4*)(xp + (size_t)r * E_ + (G) * 4);
#define PG_LOADW(WB0, WB1, G)                                    \
    _Pragma("unroll")                                            \
    for (int u = 0; u < 4; u++) {                                \
        WB0[u] = wp0[(size_t)((G) * 4 + u) * E_];                \
        WB1[u] = wp1[(size_t)((G) * 4 + u) * E_];                \
    }
#define PG_FMA(XB, WB0, WB1)                                     \
    _Pragma("unroll")                                            \
    for (int r = 0; r < ROWS; r++) {                             \
        acc0[r] = fmaf(XB[r].x, WB0[0], acc0[r]);                \
        acc0[r] = fmaf(XB[r].y, WB0[1], acc0[r]);                \
        acc0[r] = fmaf(XB[r].z, WB0[2], acc0[r]);                \
        acc0[r] = fmaf(XB[r].w, WB0[3], acc0[r]);                \
        acc1[r] = fmaf(XB[r].x, WB1[0], acc1[r]);                \
        acc1[r] = fmaf(XB[r].y, WB1[1], acc1[r]);                \
        acc1[r] = fmaf(XB[r].z, WB1[2], acc1[r]);                \
        acc1[r] = fmaf(XB[r].w, WB1[3], acc1[r]);                \
    }

    // 205 groups of 4 e's (820 = 4*205). 2-deep pipeline, reload freed buffers.
    float4 xC[ROWS], xN[ROWS];
    float wa0[4], wa1[4], wb0[4], wb1[4];
    PG_LOADX(xC, 0)
    PG_LOADX(xN, 1)
    PG_LOADW(wa0, wa1, 0)
    PG_LOADW(wb0, wb1, 1)
    for (int g = 0; g < 204; g += 2) {          // groups 0..203 in pairs
        const int p2 = g + 2;                   // <= 204
        const int p3 = (g + 3 < 205) ? g + 3 : 204;  // clamp (dup load, unused)
        PG_FMA(xC, wa0, wa1)                    // group g
        PG_LOADX(xC, p2)
        PG_LOADW(wa0, wa1, p2)
        PG_FMA(xN, wb0, wb1)                    // group g+1
        PG_LOADX(xN, p3)
        PG_LOADW(wb0, wb1, p3)
    }
    PG_FMA(xC, wa0, wa1)                        // final group 204
#undef PG_LOADX
#undef PG_LOADW
#undef PG_FMA

    {
        const int h = c0 / D_, d = c0 - h * D_;
#pragma unroll
        for (int r = 0; r < ROWS; r++)
            outp[((size_t)h * L_ + row0 + r) * D_ + d] = acc0[r];
    }
    if (a1) {
        const int h = c1 / D_, d = c1 - h * D_;
#pragma unroll
        for (int r = 0; r < ROWS; r++)
            outp[((size_t)h * L_ + row0 + r) * D_ + d] = acc1[r];
    }
}

// ================= K2: compression MLP (fp32), 3-way split hidden phase ==========
// grid (H_*LC_/4), block 256 (4 waves, one row each)
// K path: dstcTk = kc^T fp32 [h][44][512] (rows 41..43 zero), dst16 = bf16 K copy.
// V path: dstcF  = vc bf16 in MFMA B-frag order [h][16 kstep][3 nt][64 lane][8 i],
//                  n rows 41..47 zero.
__global__ __launch_bounds__(256) void k_cmlp(
    const float* __restrict__ src32,
    const float* __restrict__ w1, const float* __restrict__ b1,
    const float* __restrict__ w2, const float* __restrict__ b2,
    float* __restrict__ dstcTk, bfu* __restrict__ dst16, bfu* __restrict__ dstcF)
{
    __shared__ float in_s[4][CB_ * D_];
    __shared__ float h_s[4][20];
    const int tid = threadIdx.x, lane = tid & 63, wave = tid >> 6;
    const int row = blockIdx.x * 4 + wave;            // h*LC_ + c
    const int h = row / LC_, c = row - h * LC_;
    const size_t base = ((size_t)h * L_ + c * CB_) * D_;
    for (int i = lane; i < CB_ * D_; i += 64) {
        float fv = src32[base + i];
        in_s[wave][i] = fv;
        if (dst16) dst16[base + i] = f2b(fv);
    }
    __syncthreads();
    if (lane < 60) {
        const int col = lane % 20, chunk = lane / 20;
        const int i0 = chunk * 96;
        const int i1 = (chunk == 2) ? (CB_ * D_) : (i0 + 96);
        float a = (chunk == 0) ? b1[col] : 0.f;
        for (int i = i0; i < i1; i++) a += in_s[wave][i] * w1[i * 20 + col];
        float aa = __shfl_down(a, 20);
        float ab = __shfl_down(a, 40);
        if (lane < 20) h_s[wave][lane] = fmaxf(a + aa + ab, 0.f);
    }
    __syncthreads();
    float a = 0.f;
    if (lane < D_) {
        a = b2[lane];
#pragma unroll
        for (int j = 0; j < 20; j++) a += h_s[wave][j] * w2[j * D_ + lane];
    }
    if (dstcTk && lane < 44)
        dstcTk[((size_t)h * 44 + lane) * LC_ + c] = a;        // lanes 41..43 write 0
    if (dstcF && lane < 48)
        dstcF[((((size_t)h * 16 + (c >> 5)) * 3 + (lane >> 4)) * 64
               + (((c >> 3) & 3) * 16 + (lane & 15))) * 8 + (c & 7)] = f2b(a);
}

// ================= K3 v9: compressed attention, key-split waves ==================
// grid (QB_, H_), block 256, 2 passes of 16 q. Wave w owns keys [w*128, w*128+128)
// for ALL 16 q (no kc read duplication). kc read direct from global kc^T —
// COALESCED (64 lanes consecutive fp32). Q staged transposed in LDS. Softmax
// max/sum combined across waves exactly via tiny LDS buffers. PV: MFMA, B-frags
// coalesced from frag-ordered vcF. LDS 20.7 KB; launch_bounds(256,6) -> 6 blk/CU.
__global__ __launch_bounds__(256, 6) void k_comp(
    const float* __restrict__ q32, const float* __restrict__ kcT,
    const bfu* __restrict__ vcF, const float* __restrict__ wg,
    const float* __restrict__ bg, float* __restrict__ outp,
    double* __restrict__ bscore, float* __restrict__ bsp, int b)
{
    __shared__ __align__(16) char scr[16640];      // p_s [16][520] bfu  U  red [4][768] f32
    __shared__ __align__(16) float q_sT[44][20];   // transposed q, rows 41..43 zero
    __shared__ __align__(16) float m_buf[4][16];
    __shared__ __align__(16) float l_buf[4][16];
    __shared__ float g0_s[16];
    const int qb = blockIdx.x, h = blockIdx.y;
    const int tid = threadIdx.x, lane = tid & 63, w = tid >> 6;
    bfu* p_s = (bfu*)scr;
    float* red = (float*)scr;
    const float* kc0 = kcT + (size_t)h * 44 * LC_ + w * 128 + lane;
    const bfu* vf = vcF + (size_t)h * 16 * 3 * 64 * 8;
    const int lrow = lane & 15, lgr = lane >> 4;

    float bs0 = 0.f, bs1 = 0.f;   // block-score partials for keys w*128+lane, +64

#pragma unroll 1
    for (int pass = 0; pass < 2; pass++) {
        const int q0 = qb * 32 + pass * 16;
        // ---- stage q transposed (coalesced global reads) ----
        for (int i = tid; i < 16 * 44; i += 256) {
            int qq = i / 44, d = i - qq * 44;
            q_sT[d][qq] = (d < D_) ? q32[((size_t)h * L_ + q0 + qq) * D_ + d] : 0.f;
        }
        __syncthreads();

        if (tid < 16) {   // gates (fp32)
            float a0 = bg[0], a1g = bg[1], a2 = bg[2];
            for (int d = 0; d < D_; d++) {
                float qd = q_sT[d][tid];
                a0  += qd * wg[d * 3 + 0];
                a1g += qd * wg[d * 3 + 1];
                a2  += qd * wg[d * 3 + 2];
            }
            float gm = fmaxf(a0, fmaxf(a1g, a2));
            float e0 = __expf(a0 - gm), e1 = __expf(a1g - gm), e2 = __expf(a2 - gm);
            g0_s[tid] = e0 / (e0 + e1 + e2);
        }

        // ---- scores: s0/s1[q] for keys w*128+lane, w*128+64+lane ----
        float s0[16], s1[16];
#pragma unroll
        for (int j = 0; j < 16; j++) { s0[j] = 0.f; s1[j] = 0.f; }

        for (int d = 0; d < 44; d++) {
            float kv0 = kc0[(size_t)d * LC_];        // coalesced 256B wave-load
            float kv1 = kc0[(size_t)d * LC_ + 64];
            float4 qa = *(const float4*)&q_sT[d][0];
            float4 qbv = *(const float4*)&q_sT[d][4];
            float4 qc = *(const float4*)&q_sT[d][8];
            float4 qd = *(const float4*)&q_sT[d][12];
            s0[0]  = fmaf(qa.x,  kv0, s0[0]);  s1[0]  = fmaf(qa.x,  kv1, s1[0]);
            s0[1]  = fmaf(qa.y,  kv0, s0[1]);  s1[1]  = fmaf(qa.y,  kv1, s1[1]);
            s0[2]  = fmaf(qa.z,  kv0, s0[2]);  s1[2]  = fmaf(qa.z,  kv1, s1[2]);
            s0[3]  = fmaf(qa.w,  kv0, s0[3]);  s1[3]  = fmaf(qa.w,  kv1, s1[3]);
            s0[4]  = fmaf(qbv.x, kv0, s0[4]);  s1[4]  = fmaf(qbv.x, kv1, s1[4]);
            s0[5]  = fmaf(qbv.y, kv0, s0[5]);  s1[5]  = fmaf(qbv.y, kv1, s1[5]);
            s0[6]  = fmaf(qbv.z, kv0, s0[6]);  s1[6]  = fmaf(qbv.z, kv1, s1[6]);
            s0[7]  = fmaf(qbv.w, kv0, s0[7]);  s1[7]  = fmaf(qbv.w, kv1, s1[7]);
            s0[8]  = fmaf(qc.x,  kv0, s0[8]);  s1[8]  = fmaf(qc.x,  kv1, s1[8]);
            s0[9]  = fmaf(qc.y,  kv0, s0[9]);  s1[9]  = fmaf(qc.y,  kv1, s1[9]);
            s0[10] = fmaf(qc.z,  kv0, s0[10]); s1[10] = fmaf(qc.z,  kv1, s1[10]);
            s0[11] = fmaf(qc.w,  kv0, s0[11]); s1[11] = fmaf(qc.w,  kv1, s1[11]);
            s0[12] = fmaf(qd.x,  kv0, s0[12]); s1[12] = fmaf(qd.x,  kv1, s1[12]);
            s0[13] = fmaf(qd.y,  kv0, s0[13]); s1[13] = fmaf(qd.y,  kv1, s1[13]);
            s0[14] = fmaf(qd.z,  kv0, s0[14]); s1[14] = fmaf(qd.z,  kv1, s1[14]);
            s0[15] = fmaf(qd.w,  kv0, s0[15]); s1[15] = fmaf(qd.w,  kv1, s1[15]);
        }

        // ---- softmax: exact max (order-invariant), cross-wave via LDS ----
#pragma unroll
        for (int j = 0; j < 16; j++) {
            s0[j] *= SCALE; s1[j] *= SCALE;
            float m = fmaxf(s0[j], s1[j]);
            for (int o = 32; o; o >>= 1) m = fmaxf(m, __shfl_xor(m, o));
            if (lane == 0) m_buf[w][j] = m;
        }
        __syncthreads();
#pragma unroll
        for (int jq = 0; jq < 4; jq++) {
            float4 m0 = *(const float4*)&m_buf[0][jq * 4];
            float4 m1 = *(const float4*)&m_buf[1][jq * 4];
            float4 m2 = *(const float4*)&m_buf[2][jq * 4];
            float4 m3 = *(const float4*)&m_buf[3][jq * 4];
            float4 mg;
            mg.x = fmaxf(fmaxf(m0.x, m1.x), fmaxf(m2.x, m3.x));
            mg.y = fmaxf(fmaxf(m0.y, m1.y), fmaxf(m2.y, m3.y));
            mg.z = fmaxf(fmaxf(m0.z, m1.z), fmaxf(m2.z, m3.z));
            mg.w = fmaxf(fmaxf(m0.w, m1.w), fmaxf(m2.w, m3.w));
#pragma unroll
            for (int j2 = 0; j2 < 4; j2++) {
                const int j = jq * 4 + j2;
                const float mgv = (j2 == 0) ? mg.x : (j2 == 1) ? mg.y : (j2 == 2) ? mg.z : mg.w;
                float e0 = expf(s0[j] - mgv);
                float e1 = expf(s1[j] - mgv);
                s0[j] = e0; s1[j] = e1;
                float ls = e0 + e1;
                for (int o = 32; o; o >>= 1) ls += __shfl_xor(ls, o);
                if (lane == 0) l_buf[w][j] = ls;
            }
        }
        __syncthreads();
#pragma unroll
        for (int jq = 0; jq < 4; jq++) {
            float4 l0 = *(const float4*)&l_buf[0][jq * 4];
            float4 l1 = *(const float4*)&l_buf[1][jq * 4];
            float4 l2 = *(const float4*)&l_buf[2][jq * 4];
            float4 l3 = *(const float4*)&l_buf[3][jq * 4];
            float4 lt;
            lt.x = l0.x + l1.x + l2.x + l3.x;
            lt.y = l0.y + l1.y + l2.y + l3.y;
            lt.z = l0.z + l1.z + l2.z + l3.z;
            lt.w = l0.w + l1.w + l2.w + l3.w;
#pragma unroll
            for (int j2 = 0; j2 < 4; j2++) {
                const int j = jq * 4 + j2;
                const float ltv = (j2 == 0) ? lt.x : (j2 == 1) ? lt.y : (j2 == 2) ? lt.z : lt.w;
                const float inv = 1.f / ltv;
                float p0 = s0[j] * inv;
                float p1 = s1[j] * inv;
                p_s[j * 520 + w * 128 + lane]      = f2b(p0);
                p_s[j * 520 + w * 128 + 64 + lane] = f2b(p1);
                bs0 += p0; bs1 += p1;
            }
        }
        // wave's PV reads only its OWN p_s columns -> no barrier needed here

        // ---- PV via MFMA: wave w covers k-range [w*128, w*128+128) ----
        f32x4 acc[3];
#pragma unroll
        for (int nt = 0; nt < 3; nt++) acc[nt] = (f32x4){0.f, 0.f, 0.f, 0.f};
#pragma unroll
        for (int ks = 0; ks < 4; ks++) {
            const int k0 = w * 128 + ks * 32;
            bf16x8 av = *(const bf16x8*)&p_s[lrow * 520 + k0 + lgr * 8];
#pragma unroll
            for (int nt = 0; nt < 3; nt++) {
                bf16x8 bv = *(const bf16x8*)&vf[(((size_t)(w * 4 + ks) * 3 + nt) * 64 + lane) * 8];
                acc[nt] = __builtin_amdgcn_mfma_f32_16x16x32_bf16(av, bv, acc[nt], 0, 0, 0);
            }
        }
        __syncthreads();   // all PV p_s reads done before red overlays p_s

        // ---- cross-wave k-reduction (red overlays p_s) ----
#pragma unroll
        for (int nt = 0; nt < 3; nt++)
#pragma unroll
            for (int r = 0; r < 4; r++)
                red[w * 768 + (nt * 4 + r) * 64 + lane] = acc[nt][r];
        __syncthreads();
        for (int i = tid; i < 16 * 48; i += 256) {
            int q = i / 48, d = i - q * 48;
            if (d < D_) {
                int lg = q >> 2, r = q & 3, nt = d >> 4, lr = d & 15;
                int fi = (nt * 4 + r) * 64 + lg * 16 + lr;
                float v = red[fi] + red[768 + fi] + red[1536 + fi] + red[2304 + fi];
                outp[((size_t)(b * L_ + q0 + q)) * (H_ * D_) + h * D_ + d] = g0_s[q] * v;
            }
        }
        __syncthreads();   // red/q_sT dead before next pass
    }

    // ---- block scores: thread owns keys w*128+lane, +64 exclusively ----
    const int j0 = w * 128 + lane;
    if (bsp) {
        float* bp = &bsp[((size_t)h * QB_ + qb) * LC_];
        bp[j0] = bs0;
        bp[j0 + 64] = bs1;
    } else {
        double* bqd = &bscore[((size_t)(qb & (NREP_ - 1)) * H_ + h) * LC_];
        atomicAdd(&bqd[j0], (double)bs0);
        atomicAdd(&bqd[j0 + 64], (double)bs1);
    }
}

// ================= K4: top-k (per batch; fp32 partials or replicated fp64) ==
// grid 20, block 64
__global__ __launch_bounds__(64) void k_topk(const double* __restrict__ bs,
                                             const float* __restrict__ bsp,
                                             int* __restrict__ idxo)
{
    __shared__ double vb_[64];
    __shared__ int ib_[64];
    __shared__ int win;
    const int h = blockIdx.x, lane = threadIdx.x;
    double vals[8];
    if (bsp) {   // deterministic sequential fp64 sum of the 112 fp32 per-block partials
#pragma unroll
        for (int r = 0; r < 8; r++) vals[r] = 0.0;
        for (int pb = 0; pb < QB_; pb++) {
            const float* rowp = &bsp[((size_t)h * QB_ + pb) * LC_];
#pragma unroll
            for (int r = 0; r < 8; r++) vals[r] += (double)rowp[r * 64 + lane];
        }
    } else {     // sum the NREP_ fp64 replicas
#pragma unroll
        for (int r = 0; r < 8; r++) {
            int j = r * 64 + lane;
            double v = 0.0;
#pragma unroll
            for (int rep = 0; rep < NREP_; rep++)
                v += bs[((size_t)rep * H_ + h) * LC_ + j];
            vals[r] = v;
        }
    }
    for (int t = 0; t < TOPK_; t++) {
        double bv = -1e30; int bi = 0x7fffffff;
#pragma unroll
        for (int r = 0; r < 8; r++) {
            int j = r * 64 + lane;
            bool better = (vals[r] > bv) || (vals[r] == bv && j < bi);
            if (better) { bv = vals[r]; bi = j; }
        }
        vb_[lane] = bv; ib_[lane] = bi;
        __syncthreads();
        if (lane == 0) {
            double best = -1e30; int besti = 0x7fffffff;
            for (int u = 0; u < 64; u++) {
                if (vb_[u] > best || (vb_[u] == best && ib_[u] < besti)) { best = vb_[u]; besti = ib_[u]; }
            }
            idxo[h * TOPK_ + t] = besti;
            win = besti;
        }
        __syncthreads();
        int w = win;
#pragma unroll
        for (int r = 0; r < 8; r++)
            if ((w >> 6) == r && (w & 63) == lane) vals[r] = -1e30;
        __syncthreads();
    }
}

// ================= K5 v3: selected + window attention, 32 queries/block ==============
// grid (QB_, 20), block 256. Wave owns 8 queries in 2 groups of 4.
__global__ __launch_bounds__(256) void k_selwin(
    const float* __restrict__ q32, const bfu* __restrict__ k16,
    const float* __restrict__ v32, const int* __restrict__ idxp,
    const float* __restrict__ wg, const float* __restrict__ bg,
    float* __restrict__ outp, int b)
{
    __shared__ __align__(16) bfu ks_s[119][44];      // 112 sel + 7 window keys
    __shared__ __align__(16) float vsT[D_][130];     // fp32 v^T, pad 130
    __shared__ __align__(16) float q_s[32][44];
    __shared__ __align__(16) bfu p_s[32][NSEL_];
    __shared__ int rows_s[NSEL_];
    __shared__ float g1_s[32];
    __shared__ float pw_s[32][CB_];                  // g2-scaled window probs
    const int h = blockIdx.y;
    const int q0 = blockIdx.x * 32;
    const int tid = threadIdx.x, lane = tid & 63, wave = tid >> 6;
    const size_t kvbase = (size_t)h * L_ * D_;

    for (int i = tid; i < 32 * D_; i += 256) {
        int qq = i / D_, d = i - qq * D_;
        q_s[qq][d] = q32[((size_t)h * L_ + q0 + qq) * D_ + d];
    }
    if (tid < NSEL_) {
        int t = tid / CB_;
        rows_s[tid] = idxp[h * TOPK_ + t] * CB_ + (tid - t * CB_);
    }
    __syncthreads();

    for (int i = tid; i < 119 * D_; i += 256) {
        int key = i / D_, d = i - key * D_;
        int row = (key < NSEL_) ? rows_s[key] : (L_ - CB_ + (key - NSEL_));
        ks_s[key][d] = k16[kvbase + (size_t)row * D_ + d];
        vsT[d][key]  = v32[kvbase + (size_t)row * D_ + d];
    }
    __syncthreads();

    if (tid < 32) {   // gates + window softmax (x g2)
        float a0 = bg[0], a1 = bg[1], a2 = bg[2];
        for (int d = 0; d < D_; d++) {
            float qd = q_s[tid][d];
            a0 += qd * wg[d * 3 + 0];
            a1 += qd * wg[d * 3 + 1];
            a2 += qd * wg[d * 3 + 2];
        }
        float gm = fmaxf(a0, fmaxf(a1, a2));
        float e0 = __expf(a0 - gm), e1 = __expf(a1 - gm), e2 = __expf(a2 - gm);
        float ginv = 1.f / (e0 + e1 + e2);
        g1_s[tid] = e1 * ginv;
        float g2 = e2 * ginv;
        float sw[CB_];
        float m = -1e30f;
        for (int i = 0; i < CB_; i++) {
            float ss = 0.f;
            for (int d = 0; d < D_; d++) ss += q_s[tid][d] * b2f(ks_s[NSEL_ + i][d]);
            sw[i] = ss * SCALE;
            m = fmaxf(m, sw[i]);
        }
        float lsum = 0.f;
        for (int i = 0; i < CB_; i++) { sw[i] = __expf(sw[i] - m); lsum += sw[i]; }
        float winv = g2 / lsum;
        for (int i = 0; i < CB_; i++) pw_s[tid][i] = sw[i] * winv;
    }
    __syncthreads();

    const bool v1 = (64 + lane) < NSEL_;
    const int row1c = v1 ? (64 + lane) : 0;
    for (int g = 0; g < 2; g++) {
        const int qb2 = wave * 8 + g * 4;
        float s0[4] = {0, 0, 0, 0}, s1[4] = {0, 0, 0, 0};
        for (int dc = 0; dc < 10; dc++) {
            float4 qv[4];
#pragma unroll
            for (int qi = 0; qi < 4; qi++) qv[qi] = *(const float4*)&q_s[qb2 + qi][dc * 4];
            uint2 ra = *(const uint2*)&ks_s[lane][dc * 4];
            uint2 rb = *(const uint2*)&ks_s[row1c][dc * 4];
            float a0, a1, a2, a3, c0, c1, c2, c3;
            b2x2(ra.x, a0, a1); b2x2(ra.y, a2, a3);
            b2x2(rb.x, c0, c1); b2x2(rb.y, c2, c3);
#pragma unroll
            for (int qi = 0; qi < 4; qi++) {
                s0[qi] += qv[qi].x * a0 + qv[qi].y * a1 + qv[qi].z * a2 + qv[qi].w * a3;
                s1[qi] += qv[qi].x * c0 + qv[qi].y * c1 + qv[qi].z * c2 + qv[qi].w * c3;
            }
        }
        {
            float ka = b2f(ks_s[lane][40]);
            float kb = b2f(ks_s[row1c][40]);
#pragma unroll
            for (int qi = 0; qi < 4; qi++) {
                float qt = q_s[qb2 + qi][40];
                s0[qi] += qt * ka; s1[qi] += qt * kb;
            }
        }
#pragma unroll
        for (int qi = 0; qi < 4; qi++) {
            float a0 = s0[qi] * SCALE;
            float a1 = v1 ? s1[qi] * SCALE : -1e30f;
            float m = fmaxf(a0, a1);
            for (int o = 32; o; o >>= 1) m = fmaxf(m, __shfl_xor(m, o));
            float e0 = __expf(a0 - m);
            float e1 = v1 ? __expf(a1 - m) : 0.f;
            float lsum = e0 + e1;
            for (int o = 32; o; o >>= 1) lsum += __shfl_xor(lsum, o);
            float inv = 1.f / lsum;
            p_s[qb2 + qi][lane] = f2b(e0 * inv);
            if (v1) p_s[qb2 + qi][64 + lane] = f2b(e1 * inv);
        }
    }
    __syncthreads();

    if (lane < D_) {
        for (int g = 0; g < 2; g++) {
            const int qb2 = wave * 8 + g * 4;
            float acc[4] = {0, 0, 0, 0};
            for (int jc = 0; jc < NSEL_; jc += 4) {
                float2 va = *(const float2*)&vsT[lane][jc];
                float2 vb = *(const float2*)&vsT[lane][jc + 2];
#pragma unroll
                for (int qi = 0; qi < 4; qi++) {
                    uint2 pp = *(const uint2*)&p_s[qb2 + qi][jc];
                    float p0, p1, p2, p3;
                    b2x2(pp.x, p0, p1); b2x2(pp.y, p2, p3);
                    acc[qi] += p0 * va.x + p1 * va.y + p2 * vb.x + p3 * vb.y;
                }
            }
#pragma unroll
            for (int qi = 0; qi < 4; qi++) {
                int row = qb2 + qi;
                float wvv = 0.f;
#pragma unroll
                for (int i = 0; i < CB_; i++) wvv += pw_s[row][i] * vsT[lane][NSEL_ + i];
                float* op = &outp[((size_t)(b * L_ + q0 + row)) * (H_ * D_) + h * D_ + lane];
                *op = *op + g1_s[row] * acc[qi] + wvv;
            }
        }
    }
}

extern "C" void kernel_launch(void* const* d_in, const int* in_sizes, int n_in,
                              void* d_out, int out_size, void* d_ws, size_t ws_size,
                              hipStream_t stream) {
    (void)in_sizes; (void)n_in;
    const float* x  = (const float*)d_in[0];
    const float* wq = (const float*)d_in[1];  const float* bq = (const float*)d_in[2];
    const float* wk = (const float*)d_in[3];  const float* bk = (const float*)d_in[4];
    const float* wv = (const float*)d_in[5];  const float* bv = (const float*)d_in[6];
    const float* w1 = (const float*)d_in[7];  const float* b1 = (const float*)d_in[8];
    const float* w2 = (const float*)d_in[9];  const float* b2 = (const float*)d_in[10];
    const float* wg = (const float*)d_in[11]; const float* bg = (const float*)d_in[12];

    if (d_ws == nullptr || ws_size < WS_NEEDED) {
        k_fail<<<dim3((out_size + 255) / 256), 256, 0, stream>>>((float*)d_out, out_size);
        return;
    }

    char* ws = (char*)d_ws;
    float*  r1   = (float*)(ws + OFF_R1);    // k32 then q32
    float*  v32  = (float*)(ws + OFF_V32);
    bfu*    k16  = (bfu*)(ws + OFF_K16);
    float*  kcT  = (float*)(ws + OFF_KCT);
    bfu*    vcF  = (bfu*)(ws + OFF_VCF);
    double* bsc  = (double*)(ws + OFF_BS);
    int*    idxp = (int*)(ws + OFF_IDX);
    float*  outp = (float*)d_out;
    // atomic-free block-score partials if workspace allows (else replicated fp64 atomics)
    const bool big = (ws_size >= WS_BIG);
    float*  bsp  = big ? (float*)(ws + OFF_BSP) : (float*)nullptr;

    for (int b = 0; b < B_; b++) {
        if (!big)
            k_zero_d<<<dim3((NREP_ * H_ * LC_ + 255) / 256), 256, 0, stream>>>(bsc, NREP_ * H_ * LC_);
        // K -> r1 and V -> v32 in one fused launch
        k_proj2t<8><<<dim3(L_ / 8, 2, 2), 256, 0, stream>>>(x, wk, bk, r1, wv, bv, v32, b);
        k_cmlp<<<dim3(H_ * LC_ / 4), 256, 0, stream>>>(r1, w1, b1, w2, b2, kcT, k16, (bfu*)nullptr);
        // Q -> r1 (overwrites k32; cmlpK done)
        k_proj2t<8><<<dim3(L_ / 8, 2, 1), 256, 0, stream>>>(x, wq, bq, r1, wq, bq, r1, b);
        k_cmlp<<<dim3(H_ * LC_ / 4), 256, 0, stream>>>(v32, w1, b1, w2, b2, (float*)nullptr, (bfu*)nullptr, vcF);
        k_comp<<<dim3(QB_, H_), 256, 0, stream>>>(r1, kcT, vcF, wg, bg, outp, bsc, bsp, b);
        k_topk<<<dim3(H_), 64, 0, stream>>>(bsc, bsp, idxp);
        k_selwin<<<dim3(QB_, H_), 256, 0, stream>>>(r1, k16, v32, idxp, wg, bg, outp, b);
    }
}

// Round 9
// 1668.066 us; speedup vs baseline: 1.2715x; 1.2715x over previous
//
#include <hip/hip_runtime.h>

#define B_ 2
#define L_ 3584
#define E_ 820
#define H_ 20
#define D_ 41
#define CB_ 7
#define LC_ 512      // L_/CB_
#define TOPK_ 16
#define NSEL_ 112    // TOPK_*CB_
#define QB_ 112      // L_/32 query-blocks per head
#define NREP_ 4      // fp64 score replicas (fallback path)
#define SCALE 0.15617376188860607f  // 1/sqrt(41)

typedef unsigned short bfu;
typedef __attribute__((ext_vector_type(8))) short bf16x8;   // 8 bf16 (4 VGPRs)
typedef __attribute__((ext_vector_type(4))) float f32x4;    // MFMA C/D

__device__ __forceinline__ float b2f(bfu h) {
    union { unsigned u; float f; } c; c.u = ((unsigned)h) << 16; return c.f;
}
__device__ __forceinline__ bfu f2b(float f) {
    union { float f; unsigned u; } c; c.f = f;
    unsigned u = c.u;
    return (bfu)((u + 0x7fffu + ((u >> 16) & 1u)) >> 16);
}
__device__ __forceinline__ void b2x2(unsigned u, float& a, float& b) {
    union { unsigned u; float f; } c0, c1;
    c0.u = u << 16; c1.u = u & 0xffff0000u;
    a = c0.f; b = c1.f;
}

// ---------------- workspace layout (bytes) — per-batch reuse ----------------
#define NHLD ((size_t)H_ * L_ * D_)
#define OFF_R1   ((size_t)0)                          // fp32 (k32 then q32)
#define OFF_V32  (OFF_R1  + NHLD * 4)                 // fp32 V
#define OFF_K16  (OFF_V32 + NHLD * 4)                 // bf16 K
#define OFF_KCT  (OFF_K16 + NHLD * 2)                 // fp32 kc^T [H][44][512]
#define OFF_VCF  (OFF_KCT + (size_t)H_ * 44 * LC_ * 4)   // bf16 vc frag [H][16][3][64][8]
#define OFF_BS   (OFF_VCF + (size_t)H_ * 16 * 3 * 64 * 8 * 2)  // fp64 x NREP_ (fallback)
#define OFF_IDX  (OFF_BS  + (size_t)NREP_ * H_ * LC_ * 8)
#define WS_NEEDED (OFF_IDX + (size_t)H_ * TOPK_ * 4)  // 32,503,040 <= proven 32,830,720
// optional extension: per-block fp32 block-score partials [H][QB_][LC_]
#define OFF_BSP  WS_NEEDED
#define WS_BIG   (OFF_BSP + (size_t)H_ * QB_ * LC_ * 4)

// ================= K-fail =================
__global__ __launch_bounds__(256) void k_fail(float* __restrict__ out, int n) {
    int i = blockIdx.x * 256 + threadIdx.x;
    if (i < n) out[i] = 0.f;
}

// ================= K0: zero block scores (double, atomic-fallback mode only) ==
__global__ __launch_bounds__(256) void k_zero_d(double* __restrict__ p, int n) {
    int i = blockIdx.x * 256 + threadIdx.x;
    if (i < n) p[i] = 0.0;
}

// ================= K1 v8: projection, NO LDS, scalar-x with drain-then-issue ====
// grid (448, 2, nz), block 256. 8 rows x 512 cols per block, 2 cols/thread.
// x loads are wave-uniform (SGPR path). SMEM loads drain fully on lgkmcnt(0),
// so the ONLY correct scalar prefetch is: wait (drains x(g), issued last group)
// -> issue x(g+1) -> FMA group g. One full FMA group of latency cover, no
// full-drain penalty. w keeps the v6 A/B vmcnt pipeline. Bit-identical to
// v6/v7 (per-acc FMA order e=0..819 ascending, 4 at a time).
__global__ __launch_bounds__(256) void k_proj2(
    const float* __restrict__ x,
    const float* __restrict__ wA, const float* __restrict__ bA, float* __restrict__ outA,
    const float* __restrict__ wB, const float* __restrict__ bB, float* __restrict__ outB,
    int b)
{
    const float* w    = (blockIdx.z == 0) ? wA : wB;
    const float* bias = (blockIdx.z == 0) ? bA : bB;
    float* outp       = (blockIdx.z == 0) ? outA : outB;
    const int row0 = blockIdx.x * 8;
    const int c0 = blockIdx.y * 512 + threadIdx.x;   // always < 820
    const int c1 = c0 + 256;
    const bool a1 = (c1 < E_);
    const int cc1 = a1 ? c1 : (E_ - 1);
    float acc0[8], acc1[8];
    const float bb0 = bias[c0];
    const float bb1 = bias[cc1];
#pragma unroll
    for (int r = 0; r < 8; r++) { acc0[r] = bb0; acc1[r] = bb1; }

    const float* xp  = x + ((size_t)b * L_ + row0) * E_;  // uniform row-block base
    const float* wp0 = w + c0;
    const float* wp1 = w + cc1;

#define PG_LOADX(XB, G)                                          \
    _Pragma("unroll")                                            \
    for (int r = 0; r < 8; r++)                                  \
        XB[r] = *(const float4*)(xp + (size_t)r * E_ + (G) * 4);
#define PG_LOADW(WB0, WB1, G)                                    \
    _Pragma("unroll")                                            \
    for (int u = 0; u < 4; u++) {                                \
        WB0[u] = wp0[(size_t)((G) * 4 + u) * E_];                \
        WB1[u] = wp1[(size_t)((G) * 4 + u) * E_];                \
    }
#define PG_FMA(XB, WB0, WB1)                                     \
    _Pragma("unroll")                                            \
    for (int r = 0; r < 8; r++) {                                \
        acc0[r] = fmaf(XB[r].x, WB0[0], acc0[r]);                \
        acc0[r] = fmaf(XB[r].y, WB0[1], acc0[r]);                \
        acc0[r] = fmaf(XB[r].z, WB0[2], acc0[r]);                \
        acc0[r] = fmaf(XB[r].w, WB0[3], acc0[r]);                \
        acc1[r] = fmaf(XB[r].x, WB1[0], acc1[r]);                \
        acc1[r] = fmaf(XB[r].y, WB1[1], acc1[r]);                \
        acc1[r] = fmaf(XB[r].z, WB1[2], acc1[r]);                \
        acc1[r] = fmaf(XB[r].w, WB1[3], acc1[r]);                \
    }
#define XDRAIN asm volatile("s_waitcnt lgkmcnt(0)" ::: "memory");

    // 205 groups of 4 e's (820 = 4*205).
    float4 xa[8], xb[8];          // wave-uniform -> SGPRs
    float wa0[4], wa1[4], wb0[4], wb1[4];
    PG_LOADX(xa, 0)
    PG_LOADW(wa0, wa1, 0)
    PG_LOADW(wb0, wb1, 1)
    for (int g = 0; g < 204; g += 2) {          // g = 0,2,...,202
        const int p3 = (g + 3 < 205) ? g + 3 : 204;  // clamp (dup load, unused)
        XDRAIN                                  // drains x(g) only
        PG_LOADX(xb, g + 1)                     // prefetch odd group's x
        PG_FMA(xa, wa0, wa1)                    // group g
        PG_LOADW(wa0, wa1, g + 2)               // w for g+2 (vmcnt path)
        XDRAIN                                  // drains x(g+1) only
        PG_LOADX(xa, g + 2)                     // prefetch even group's x
        PG_FMA(xb, wb0, wb1)                    // group g+1
        PG_LOADW(wb0, wb1, p3)                  // w for g+3
    }
    XDRAIN
    PG_FMA(xa, wa0, wa1)                        // final group 204
#undef PG_LOADX
#undef PG_LOADW
#undef PG_FMA
#undef XDRAIN

    {
        const int h = c0 / D_, d = c0 - h * D_;
#pragma unroll
        for (int r = 0; r < 8; r++)
            outp[((size_t)h * L_ + row0 + r) * D_ + d] = acc0[r];
    }
    if (a1) {
        const int h = c1 / D_, d = c1 - h * D_;
#pragma unroll
        for (int r = 0; r < 8; r++)
            outp[((size_t)h * L_ + row0 + r) * D_ + d] = acc1[r];
    }
}

// ================= K2: compression MLP (fp32), 3-way split hidden phase ==========
// grid (H_*LC_/4), block 256 (4 waves, one row each)
// K path: dstcTk = kc^T fp32 [h][44][512] (rows 41..43 zero), dst16 = bf16 K copy.
// V path: dstcF  = vc bf16 in MFMA B-frag order [h][16 kstep][3 nt][64 lane][8 i],
//                  n rows 41..47 zero.
__global__ __launch_bounds__(256) void k_cmlp(
    const float* __restrict__ src32,
    const float* __restrict__ w1, const float* __restrict__ b1,
    const float* __restrict__ w2, const float* __restrict__ b2,
    float* __restrict__ dstcTk, bfu* __restrict__ dst16, bfu* __restrict__ dstcF)
{
    __shared__ float in_s[4][CB_ * D_];
    __shared__ float h_s[4][20];
    const int tid = threadIdx.x, lane = tid & 63, wave = tid >> 6;
    const int row = blockIdx.x * 4 + wave;            // h*LC_ + c
    const int h = row / LC_, c = row - h * LC_;
    const size_t base = ((size_t)h * L_ + c * CB_) * D_;
    for (int i = lane; i < CB_ * D_; i += 64) {
        float fv = src32[base + i];
        in_s[wave][i] = fv;
        if (dst16) dst16[base + i] = f2b(fv);
    }
    __syncthreads();
    if (lane < 60) {
        const int col = lane % 20, chunk = lane / 20;
        const int i0 = chunk * 96;
        const int i1 = (chunk == 2) ? (CB_ * D_) : (i0 + 96);
        float a = (chunk == 0) ? b1[col] : 0.f;
        for (int i = i0; i < i1; i++) a += in_s[wave][i] * w1[i * 20 + col];
        float aa = __shfl_down(a, 20);
        float ab = __shfl_down(a, 40);
        if (lane < 20) h_s[wave][lane] = fmaxf(a + aa + ab, 0.f);
    }
    __syncthreads();
    float a = 0.f;
    if (lane < D_) {
        a = b2[lane];
#pragma unroll
        for (int j = 0; j < 20; j++) a += h_s[wave][j] * w2[j * D_ + lane];
    }
    if (dstcTk && lane < 44)
        dstcTk[((size_t)h * 44 + lane) * LC_ + c] = a;        // lanes 41..43 write 0
    if (dstcF && lane < 48)
        dstcF[((((size_t)h * 16 + (c >> 5)) * 3 + (lane >> 4)) * 64
               + (((c >> 3) & 3) * 16 + (lane & 15))) * 8 + (c & 7)] = f2b(a);
}

// ================= K3 v9: compressed attention, key-split waves ==================
// grid (QB_, H_), block 256, 2 passes of 16 q. Wave w owns keys [w*128, w*128+128)
// for ALL 16 q (no kc read duplication). kc read direct from global kc^T —
// COALESCED (64 lanes consecutive fp32). Q staged transposed in LDS. Softmax
// max/sum combined across waves exactly via tiny LDS buffers. PV: MFMA, B-frags
// coalesced from frag-ordered vcF. LDS 20.7 KB; launch_bounds(256,6) -> 6 blk/CU.
__global__ __launch_bounds__(256, 6) void k_comp(
    const float* __restrict__ q32, const float* __restrict__ kcT,
    const bfu* __restrict__ vcF, const float* __restrict__ wg,
    const float* __restrict__ bg, float* __restrict__ outp,
    double* __restrict__ bscore, float* __restrict__ bsp, int b)
{
    __shared__ __align__(16) char scr[16640];      // p_s [16][520] bfu  U  red [4][768] f32
    __shared__ __align__(16) float q_sT[44][20];   // transposed q, rows 41..43 zero
    __shared__ __align__(16) float m_buf[4][16];
    __shared__ __align__(16) float l_buf[4][16];
    __shared__ float g0_s[16];
    const int qb = blockIdx.x, h = blockIdx.y;
    const int tid = threadIdx.x, lane = tid & 63, w = tid >> 6;
    bfu* p_s = (bfu*)scr;
    float* red = (float*)scr;
    const float* kc0 = kcT + (size_t)h * 44 * LC_ + w * 128 + lane;
    const bfu* vf = vcF + (size_t)h * 16 * 3 * 64 * 8;
    const int lrow = lane & 15, lgr = lane >> 4;

    float bs0 = 0.f, bs1 = 0.f;   // block-score partials for keys w*128+lane, +64

#pragma unroll 1
    for (int pass = 0; pass < 2; pass++) {
        const int q0 = qb * 32 + pass * 16;
        // ---- stage q transposed (coalesced global reads) ----
        for (int i = tid; i < 16 * 44; i += 256) {
            int qq = i / 44, d = i - qq * 44;
            q_sT[d][qq] = (d < D_) ? q32[((size_t)h * L_ + q0 + qq) * D_ + d] : 0.f;
        }
        __syncthreads();

        if (tid < 16) {   // gates (fp32)
            float a0 = bg[0], a1g = bg[1], a2 = bg[2];
            for (int d = 0; d < D_; d++) {
                float qd = q_sT[d][tid];
                a0  += qd * wg[d * 3 + 0];
                a1g += qd * wg[d * 3 + 1];
                a2  += qd * wg[d * 3 + 2];
            }
            float gm = fmaxf(a0, fmaxf(a1g, a2));
            float e0 = __expf(a0 - gm), e1 = __expf(a1g - gm), e2 = __expf(a2 - gm);
            g0_s[tid] = e0 / (e0 + e1 + e2);
        }

        // ---- scores: s0/s1[q] for keys w*128+lane, w*128+64+lane ----
        float s0[16], s1[16];
#pragma unroll
        for (int j = 0; j < 16; j++) { s0[j] = 0.f; s1[j] = 0.f; }

        for (int d = 0; d < 44; d++) {
            float kv0 = kc0[(size_t)d * LC_];        // coalesced 256B wave-load
            float kv1 = kc0[(size_t)d * LC_ + 64];
            float4 qa = *(const float4*)&q_sT[d][0];
            float4 qbv = *(const float4*)&q_sT[d][4];
            float4 qc = *(const float4*)&q_sT[d][8];
            float4 qd = *(const float4*)&q_sT[d][12];
            s0[0]  = fmaf(qa.x,  kv0, s0[0]);  s1[0]  = fmaf(qa.x,  kv1, s1[0]);
            s0[1]  = fmaf(qa.y,  kv0, s0[1]);  s1[1]  = fmaf(qa.y,  kv1, s1[1]);
            s0[2]  = fmaf(qa.z,  kv0, s0[2]);  s1[2]  = fmaf(qa.z,  kv1, s1[2]);
            s0[3]  = fmaf(qa.w,  kv0, s0[3]);  s1[3]  = fmaf(qa.w,  kv1, s1[3]);
            s0[4]  = fmaf(qbv.x, kv0, s0[4]);  s1[4]  = fmaf(qbv.x, kv1, s1[4]);
            s0[5]  = fmaf(qbv.y, kv0, s0[5]);  s1[5]  = fmaf(qbv.y, kv1, s1[5]);
            s0[6]  = fmaf(qbv.z, kv0, s0[6]);  s1[6]  = fmaf(qbv.z, kv1, s1[6]);
            s0[7]  = fmaf(qbv.w, kv0, s0[7]);  s1[7]  = fmaf(qbv.w, kv1, s1[7]);
            s0[8]  = fmaf(qc.x,  kv0, s0[8]);  s1[8]  = fmaf(qc.x,  kv1, s1[8]);
            s0[9]  = fmaf(qc.y,  kv0, s0[9]);  s1[9]  = fmaf(qc.y,  kv1, s1[9]);
            s0[10] = fmaf(qc.z,  kv0, s0[10]); s1[10] = fmaf(qc.z,  kv1, s1[10]);
            s0[11] = fmaf(qc.w,  kv0, s0[11]); s1[11] = fmaf(qc.w,  kv1, s1[11]);
            s0[12] = fmaf(qd.x,  kv0, s0[12]); s1[12] = fmaf(qd.x,  kv1, s1[12]);
            s0[13] = fmaf(qd.y,  kv0, s0[13]); s1[13] = fmaf(qd.y,  kv1, s1[13]);
            s0[14] = fmaf(qd.z,  kv0, s0[14]); s1[14] = fmaf(qd.z,  kv1, s1[14]);
            s0[15] = fmaf(qd.w,  kv0, s0[15]); s1[15] = fmaf(qd.w,  kv1, s1[15]);
        }

        // ---- softmax: exact max (order-invariant), cross-wave via LDS ----
#pragma unroll
        for (int j = 0; j < 16; j++) {
            s0[j] *= SCALE; s1[j] *= SCALE;
            float m = fmaxf(s0[j], s1[j]);
            for (int o = 32; o; o >>= 1) m = fmaxf(m, __shfl_xor(m, o));
            if (lane == 0) m_buf[w][j] = m;
        }
        __syncthreads();
#pragma unroll
        for (int jq = 0; jq < 4; jq++) {
            float4 m0 = *(const float4*)&m_buf[0][jq * 4];
            float4 m1 = *(const float4*)&m_buf[1][jq * 4];
            float4 m2 = *(const float4*)&m_buf[2][jq * 4];
            float4 m3 = *(const float4*)&m_buf[3][jq * 4];
            float4 mg;
            mg.x = fmaxf(fmaxf(m0.x, m1.x), fmaxf(m2.x, m3.x));
            mg.y = fmaxf(fmaxf(m0.y, m1.y), fmaxf(m2.y, m3.y));
            mg.z = fmaxf(fmaxf(m0.z, m1.z), fmaxf(m2.z, m3.z));
            mg.w = fmaxf(fmaxf(m0.w, m1.w), fmaxf(m2.w, m3.w));
#pragma unroll
            for (int j2 = 0; j2 < 4; j2++) {
                const int j = jq * 4 + j2;
                const float mgv = (j2 == 0) ? mg.x : (j2 == 1) ? mg.y : (j2 == 2) ? mg.z : mg.w;
                float e0 = expf(s0[j] - mgv);
                float e1 = expf(s1[j] - mgv);
                s0[j] = e0; s1[j] = e1;
                float ls = e0 + e1;
                for (int o = 32; o; o >>= 1) ls += __shfl_xor(ls, o);
                if (lane == 0) l_buf[w][j] = ls;
            }
        }
        __syncthreads();
#pragma unroll
        for (int jq = 0; jq < 4; jq++) {
            float4 l0 = *(const float4*)&l_buf[0][jq * 4];
            float4 l1 = *(const float4*)&l_buf[1][jq * 4];
            float4 l2 = *(const float4*)&l_buf[2][jq * 4];
            float4 l3 = *(const float4*)&l_buf[3][jq * 4];
            float4 lt;
            lt.x = l0.x + l1.x + l2.x + l3.x;
            lt.y = l0.y + l1.y + l2.y + l3.y;
            lt.z = l0.z + l1.z + l2.z + l3.z;
            lt.w = l0.w + l1.w + l2.w + l3.w;
#pragma unroll
            for (int j2 = 0; j2 < 4; j2++) {
                const int j = jq * 4 + j2;
                const float ltv = (j2 == 0) ? lt.x : (j2 == 1) ? lt.y : (j2 == 2) ? lt.z : lt.w;
                const float inv = 1.f / ltv;
                float p0 = s0[j] * inv;
                float p1 = s1[j] * inv;
                p_s[j * 520 + w * 128 + lane]      = f2b(p0);
                p_s[j * 520 + w * 128 + 64 + lane] = f2b(p1);
                bs0 += p0; bs1 += p1;
            }
        }
        // wave's PV reads only its OWN p_s columns -> no barrier needed here

        // ---- PV via MFMA: wave w covers k-range [w*128, w*128+128) ----
        f32x4 acc[3];
#pragma unroll
        for (int nt = 0; nt < 3; nt++) acc[nt] = (f32x4){0.f, 0.f, 0.f, 0.f};
#pragma unroll
        for (int ks = 0; ks < 4; ks++) {
            const int k0 = w * 128 + ks * 32;
            bf16x8 av = *(const bf16x8*)&p_s[lrow * 520 + k0 + lgr * 8];
#pragma unroll
            for (int nt = 0; nt < 3; nt++) {
                bf16x8 bv = *(const bf16x8*)&vf[(((size_t)(w * 4 + ks) * 3 + nt) * 64 + lane) * 8];
                acc[nt] = __builtin_amdgcn_mfma_f32_16x16x32_bf16(av, bv, acc[nt], 0, 0, 0);
            }
        }
        __syncthreads();   // all PV p_s reads done before red overlays p_s

        // ---- cross-wave k-reduction (red overlays p_s) ----
#pragma unroll
        for (int nt = 0; nt < 3; nt++)
#pragma unroll
            for (int r = 0; r < 4; r++)
                red[w * 768 + (nt * 4 + r) * 64 + lane] = acc[nt][r];
        __syncthreads();
        for (int i = tid; i < 16 * 48; i += 256) {
            int q = i / 48, d = i - q * 48;
            if (d < D_) {
                int lg = q >> 2, r = q & 3, nt = d >> 4, lr = d & 15;
                int fi = (nt * 4 + r) * 64 + lg * 16 + lr;
                float v = red[fi] + red[768 + fi] + red[1536 + fi] + red[2304 + fi];
                outp[((size_t)(b * L_ + q0 + q)) * (H_ * D_) + h * D_ + d] = g0_s[q] * v;
            }
        }
        __syncthreads();   // red/q_sT dead before next pass
    }

    // ---- block scores: thread owns keys w*128+lane, +64 exclusively ----
    const int j0 = w * 128 + lane;
    if (bsp) {
        float* bp = &bsp[((size_t)h * QB_ + qb) * LC_];
        bp[j0] = bs0;
        bp[j0 + 64] = bs1;
    } else {
        double* bqd = &bscore[((size_t)(qb & (NREP_ - 1)) * H_ + h) * LC_];
        atomicAdd(&bqd[j0], (double)bs0);
        atomicAdd(&bqd[j0 + 64], (double)bs1);
    }
}

// ================= K4: top-k (per batch; fp32 partials or replicated fp64) ==
// grid 20, block 64
__global__ __launch_bounds__(64) void k_topk(const double* __restrict__ bs,
                                             const float* __restrict__ bsp,
                                             int* __restrict__ idxo)
{
    __shared__ double vb_[64];
    __shared__ int ib_[64];
    __shared__ int win;
    const int h = blockIdx.x, lane = threadIdx.x;
    double vals[8];
    if (bsp) {   // deterministic sequential fp64 sum of the 112 fp32 per-block partials
#pragma unroll
        for (int r = 0; r < 8; r++) vals[r] = 0.0;
        for (int pb = 0; pb < QB_; pb++) {
            const float* rowp = &bsp[((size_t)h * QB_ + pb) * LC_];
#pragma unroll
            for (int r = 0; r < 8; r++) vals[r] += (double)rowp[r * 64 + lane];
        }
    } else {     // sum the NREP_ fp64 replicas
#pragma unroll
        for (int r = 0; r < 8; r++) {
            int j = r * 64 + lane;
            double v = 0.0;
#pragma unroll
            for (int rep = 0; rep < NREP_; rep++)
                v += bs[((size_t)rep * H_ + h) * LC_ + j];
            vals[r] = v;
        }
    }
    for (int t = 0; t < TOPK_; t++) {
        double bv = -1e30; int bi = 0x7fffffff;
#pragma unroll
        for (int r = 0; r < 8; r++) {
            int j = r * 64 + lane;
            bool better = (vals[r] > bv) || (vals[r] == bv && j < bi);
            if (better) { bv = vals[r]; bi = j; }
        }
        vb_[lane] = bv; ib_[lane] = bi;
        __syncthreads();
        if (lane == 0) {
            double best = -1e30; int besti = 0x7fffffff;
            for (int u = 0; u < 64; u++) {
                if (vb_[u] > best || (vb_[u] == best && ib_[u] < besti)) { best = vb_[u]; besti = ib_[u]; }
            }
            idxo[h * TOPK_ + t] = besti;
            win = besti;
        }
        __syncthreads();
        int w = win;
#pragma unroll
        for (int r = 0; r < 8; r++)
            if ((w >> 6) == r && (w & 63) == lane) vals[r] = -1e30;
        __syncthreads();
    }
}

// ================= K5 v3: selected + window attention, 32 queries/block ==============
// grid (QB_, 20), block 256. Wave owns 8 queries in 2 groups of 4.
__global__ __launch_bounds__(256) void k_selwin(
    const float* __restrict__ q32, const bfu* __restrict__ k16,
    const float* __restrict__ v32, const int* __restrict__ idxp,
    const float* __restrict__ wg, const float* __restrict__ bg,
    float* __restrict__ outp, int b)
{
    __shared__ __align__(16) bfu ks_s[119][44];      // 112 sel + 7 window keys
    __shared__ __align__(16) float vsT[D_][130];     // fp32 v^T, pad 130
    __shared__ __align__(16) float q_s[32][44];
    __shared__ __align__(16) bfu p_s[32][NSEL_];
    __shared__ int rows_s[NSEL_];
    __shared__ float g1_s[32];
    __shared__ float pw_s[32][CB_];                  // g2-scaled window probs
    const int h = blockIdx.y;
    const int q0 = blockIdx.x * 32;
    const int tid = threadIdx.x, lane = tid & 63, wave = tid >> 6;
    const size_t kvbase = (size_t)h * L_ * D_;

    for (int i = tid; i < 32 * D_; i += 256) {
        int qq = i / D_, d = i - qq * D_;
        q_s[qq][d] = q32[((size_t)h * L_ + q0 + qq) * D_ + d];
    }
    if (tid < NSEL_) {
        int t = tid / CB_;
        rows_s[tid] = idxp[h * TOPK_ + t] * CB_ + (tid - t * CB_);
    }
    __syncthreads();

    for (int i = tid; i < 119 * D_; i += 256) {
        int key = i / D_, d = i - key * D_;
        int row = (key < NSEL_) ? rows_s[key] : (L_ - CB_ + (key - NSEL_));
        ks_s[key][d] = k16[kvbase + (size_t)row * D_ + d];
        vsT[d][key]  = v32[kvbase + (size_t)row * D_ + d];
    }
    __syncthreads();

    if (tid < 32) {   // gates + window softmax (x g2)
        float a0 = bg[0], a1 = bg[1], a2 = bg[2];
        for (int d = 0; d < D_; d++) {
            float qd = q_s[tid][d];
            a0 += qd * wg[d * 3 + 0];
            a1 += qd * wg[d * 3 + 1];
            a2 += qd * wg[d * 3 + 2];
        }
        float gm = fmaxf(a0, fmaxf(a1, a2));
        float e0 = __expf(a0 - gm), e1 = __expf(a1 - gm), e2 = __expf(a2 - gm);
        float ginv = 1.f / (e0 + e1 + e2);
        g1_s[tid] = e1 * ginv;
        float g2 = e2 * ginv;
        float sw[CB_];
        float m = -1e30f;
        for (int i = 0; i < CB_; i++) {
            float ss = 0.f;
            for (int d = 0; d < D_; d++) ss += q_s[tid][d] * b2f(ks_s[NSEL_ + i][d]);
            sw[i] = ss * SCALE;
            m = fmaxf(m, sw[i]);
        }
        float lsum = 0.f;
        for (int i = 0; i < CB_; i++) { sw[i] = __expf(sw[i] - m); lsum += sw[i]; }
        float winv = g2 / lsum;
        for (int i = 0; i < CB_; i++) pw_s[tid][i] = sw[i] * winv;
    }
    __syncthreads();

    const bool v1 = (64 + lane) < NSEL_;
    const int row1c = v1 ? (64 + lane) : 0;
    for (int g = 0; g < 2; g++) {
        const int qb2 = wave * 8 + g * 4;
        float s0[4] = {0, 0, 0, 0}, s1[4] = {0, 0, 0, 0};
        for (int dc = 0; dc < 10; dc++) {
            float4 qv[4];
#pragma unroll
            for (int qi = 0; qi < 4; qi++) qv[qi] = *(const float4*)&q_s[qb2 + qi][dc * 4];
            uint2 ra = *(const uint2*)&ks_s[lane][dc * 4];
            uint2 rb = *(const uint2*)&ks_s[row1c][dc * 4];
            float a0, a1, a2, a3, c0, c1, c2, c3;
            b2x2(ra.x, a0, a1); b2x2(ra.y, a2, a3);
            b2x2(rb.x, c0, c1); b2x2(rb.y, c2, c3);
#pragma unroll
            for (int qi = 0; qi < 4; qi++) {
                s0[qi] += qv[qi].x * a0 + qv[qi].y * a1 + qv[qi].z * a2 + qv[qi].w * a3;
                s1[qi] += qv[qi].x * c0 + qv[qi].y * c1 + qv[qi].z * c2 + qv[qi].w * c3;
            }
        }
        {
            float ka = b2f(ks_s[lane][40]);
            float kb = b2f(ks_s[row1c][40]);
#pragma unroll
            for (int qi = 0; qi < 4; qi++) {
                float qt = q_s[qb2 + qi][40];
                s0[qi] += qt * ka; s1[qi] += qt * kb;
            }
        }
#pragma unroll
        for (int qi = 0; qi < 4; qi++) {
            float a0 = s0[qi] * SCALE;
            float a1 = v1 ? s1[qi] * SCALE : -1e30f;
            float m = fmaxf(a0, a1);
            for (int o = 32; o; o >>= 1) m = fmaxf(m, __shfl_xor(m, o));
            float e0 = __expf(a0 - m);
            float e1 = v1 ? __expf(a1 - m) : 0.f;
            float lsum = e0 + e1;
            for (int o = 32; o; o >>= 1) lsum += __shfl_xor(lsum, o);
            float inv = 1.f / lsum;
            p_s[qb2 + qi][lane] = f2b(e0 * inv);
            if (v1) p_s[qb2 + qi][64 + lane] = f2b(e1 * inv);
        }
    }
    __syncthreads();

    if (lane < D_) {
        for (int g = 0; g < 2; g++) {
            const int qb2 = wave * 8 + g * 4;
            float acc[4] = {0, 0, 0, 0};
            for (int jc = 0; jc < NSEL_; jc += 4) {
                float2 va = *(const float2*)&vsT[lane][jc];
                float2 vb = *(const float2*)&vsT[lane][jc + 2];
#pragma unroll
                for (int qi = 0; qi < 4; qi++) {
                    uint2 pp = *(const uint2*)&p_s[qb2 + qi][jc];
                    float p0, p1, p2, p3;
                    b2x2(pp.x, p0, p1); b2x2(pp.y, p2, p3);
                    acc[qi] += p0 * va.x + p1 * va.y + p2 * vb.x + p3 * vb.y;
                }
            }
#pragma unroll
            for (int qi = 0; qi < 4; qi++) {
                int row = qb2 + qi;
                float wvv = 0.f;
#pragma unroll
                for (int i = 0; i < CB_; i++) wvv += pw_s[row][i] * vsT[lane][NSEL_ + i];
                float* op = &outp[((size_t)(b * L_ + q0 + row)) * (H_ * D_) + h * D_ + lane];
                *op = *op + g1_s[row] * acc[qi] + wvv;
            }
        }
    }
}

extern "C" void kernel_launch(void* const* d_in, const int* in_sizes, int n_in,
                              void* d_out, int out_size, void* d_ws, size_t ws_size,
                              hipStream_t stream) {
    (void)in_sizes; (void)n_in;
    const float* x  = (const float*)d_in[0];
    const float* wq = (const float*)d_in[1];  const float* bq = (const float*)d_in[2];
    const float* wk = (const float*)d_in[3];  const float* bk = (const float*)d_in[4];
    const float* wv = (const float*)d_in[5];  const float* bv = (const float*)d_in[6];
    const float* w1 = (const float*)d_in[7];  const float* b1 = (const float*)d_in[8];
    const float* w2 = (const float*)d_in[9];  const float* b2 = (const float*)d_in[10];
    const float* wg = (const float*)d_in[11]; const float* bg = (const float*)d_in[12];

    if (d_ws == nullptr || ws_size < WS_NEEDED) {
        k_fail<<<dim3((out_size + 255) / 256), 256, 0, stream>>>((float*)d_out, out_size);
        return;
    }

    char* ws = (char*)d_ws;
    float*  r1   = (float*)(ws + OFF_R1);    // k32 then q32
    float*  v32  = (float*)(ws + OFF_V32);
    bfu*    k16  = (bfu*)(ws + OFF_K16);
    float*  kcT  = (float*)(ws + OFF_KCT);
    bfu*    vcF  = (bfu*)(ws + OFF_VCF);
    double* bsc  = (double*)(ws + OFF_BS);
    int*    idxp = (int*)(ws + OFF_IDX);
    float*  outp = (float*)d_out;
    // atomic-free block-score partials if workspace allows (else replicated fp64 atomics)
    const bool big = (ws_size >= WS_BIG);
    float*  bsp  = big ? (float*)(ws + OFF_BSP) : (float*)nullptr;

    for (int b = 0; b < B_; b++) {
        if (!big)
            k_zero_d<<<dim3((NREP_ * H_ * LC_ + 255) / 256), 256, 0, stream>>>(bsc, NREP_ * H_ * LC_);
        // K -> r1 and V -> v32 in one fused launch
        k_proj2<<<dim3(L_ / 8, 2, 2), 256, 0, stream>>>(x, wk, bk, r1, wv, bv, v32, b);
        k_cmlp<<<dim3(H_ * LC_ / 4), 256, 0, stream>>>(r1, w1, b1, w2, b2, kcT, k16, (bfu*)nullptr);
        // Q -> r1 (overwrites k32; cmlpK done)
        k_proj2<<<dim3(L_ / 8, 2, 1), 256, 0, stream>>>(x, wq, bq, r1, wq, bq, r1, b);
        k_cmlp<<<dim3(H_ * LC_ / 4), 256, 0, stream>>>(v32, w1, b1, w2, b2, (float*)nullptr, (bfu*)nullptr, vcF);
        k_comp<<<dim3(QB_, H_), 256, 0, stream>>>(r1, kcT, vcF, wg, bg, outp, bsc, bsp, b);
        k_topk<<<dim3(H_), 64, 0, stream>>>(bsc, bsp, idxp);
        k_selwin<<<dim3(QB_, H_), 256, 0, stream>>>(r1, k16, v32, idxp, wg, bg, outp, b);
    }
}

// Round 10
// 1520.391 us; speedup vs baseline: 1.3950x; 1.0971x over previous
//
#include <hip/hip_runtime.h>

#define B_ 2
#define L_ 3584
#define E_ 820
#define H_ 20
#define D_ 41
#define CB_ 7
#define LC_ 512      // L_/CB_
#define TOPK_ 16
#define NSEL_ 112    // TOPK_*CB_
#define QB_ 112      // L_/32 query-blocks per head
#define NREP_ 4      // fp64 score replicas (fallback path)
#define SCALE 0.15617376188860607f  // 1/sqrt(41)

typedef unsigned short bfu;
typedef __attribute__((ext_vector_type(8))) short bf16x8;   // 8 bf16 (4 VGPRs)
typedef __attribute__((ext_vector_type(4))) float f32x4;    // MFMA C/D

__device__ __forceinline__ float b2f(bfu h) {
    union { unsigned u; float f; } c; c.u = ((unsigned)h) << 16; return c.f;
}
__device__ __forceinline__ bfu f2b(float f) {
    union { float f; unsigned u; } c; c.f = f;
    unsigned u = c.u;
    return (bfu)((u + 0x7fffu + ((u >> 16) & 1u)) >> 16);
}
__device__ __forceinline__ void b2x2(unsigned u, float& a, float& b) {
    union { unsigned u; float f; } c0, c1;
    c0.u = u << 16; c1.u = u & 0xffff0000u;
    a = c0.f; b = c1.f;
}

// ---------------- workspace layout (bytes) — per-batch reuse ----------------
#define NHLD ((size_t)H_ * L_ * D_)
#define OFF_R1   ((size_t)0)                          // fp32 (k32 then q32)
#define OFF_V32  (OFF_R1  + NHLD * 4)                 // fp32 V
#define OFF_K16  (OFF_V32 + NHLD * 4)                 // bf16 K
#define OFF_KCT  (OFF_K16 + NHLD * 2)                 // fp32 kc^T [H][44][512]
#define OFF_VCF  (OFF_KCT + (size_t)H_ * 44 * LC_ * 4)   // bf16 vc frag [H][16][3][64][8]
#define OFF_BS   (OFF_VCF + (size_t)H_ * 16 * 3 * 64 * 8 * 2)  // fp64 x NREP_ (fallback)
#define OFF_IDX  (OFF_BS  + (size_t)NREP_ * H_ * LC_ * 8)
#define WS_NEEDED (OFF_IDX + (size_t)H_ * TOPK_ * 4)  // 32,503,040 <= proven 32,830,720
// optional extension: per-block fp32 block-score partials [H][QB_][LC_]
#define OFF_BSP  WS_NEEDED
#define WS_BIG   (OFF_BSP + (size_t)H_ * QB_ * LC_ * 4)

// ================= K-fail =================
__global__ __launch_bounds__(256) void k_fail(float* __restrict__ out, int n) {
    int i = blockIdx.x * 256 + threadIdx.x;
    if (i < n) out[i] = 0.f;
}

// ================= K0: zero block scores (double, atomic-fallback mode only) ==
__global__ __launch_bounds__(256) void k_zero_d(double* __restrict__ p, int n) {
    int i = blockIdx.x * 256 + threadIdx.x;
    if (i < n) p[i] = 0.0;
}

// ================= K1 v6 (round-7 proven, 212us KV): NO LDS, scalar-x ==========
// grid (448, 2, nz), block 256. 8 rows x 512 cols per block, 2 cols/thread.
// x addresses are wave-uniform -> compiler emits s_load_dwordx4 (scalar path):
// zero LDS, zero barriers, zero ds_reads. w keeps the A/B 2-deep vector-load
// pipeline. e-loop 0..819 in 4-e groups (820 = 4*205, no tail) -> per-acc FMA
// order identical across versions -> bit-identical outputs.
__global__ __launch_bounds__(256) void k_proj2(
    const float* __restrict__ x,
    const float* __restrict__ wA, const float* __restrict__ bA, float* __restrict__ outA,
    const float* __restrict__ wB, const float* __restrict__ bB, float* __restrict__ outB,
    int b)
{
    const float* w    = (blockIdx.z == 0) ? wA : wB;
    const float* bias = (blockIdx.z == 0) ? bA : bB;
    float* outp       = (blockIdx.z == 0) ? outA : outB;
    const int row0 = blockIdx.x * 8;
    const int c0 = blockIdx.y * 512 + threadIdx.x;   // always < 820
    const int c1 = c0 + 256;
    const bool a1 = (c1 < E_);
    const int cc1 = a1 ? c1 : (E_ - 1);
    float acc0[8], acc1[8];
    const float bb0 = bias[c0];
    const float bb1 = bias[cc1];
#pragma unroll
    for (int r = 0; r < 8; r++) { acc0[r] = bb0; acc1[r] = bb1; }

    const float* xp  = x + ((size_t)b * L_ + row0) * E_;  // uniform row-block base
    const float* wp0 = w + c0;
    const float* wp1 = w + cc1;

#define PROJ_GROUP(W0, W1, EBASE, PREFG)                                    \
    {                                                                       \
        float n0[4], n1[4];                                                 \
        const int pg = ((PREFG) < 204) ? (PREFG) : 204;                     \
        _Pragma("unroll")                                                   \
        for (int u = 0; u < 4; u++) {                                       \
            n0[u] = wp0[(size_t)(pg * 4 + u) * E_];                         \
            n1[u] = wp1[(size_t)(pg * 4 + u) * E_];                         \
        }                                                                   \
        _Pragma("unroll")                                                   \
        for (int r = 0; r < 8; r++) {                                       \
            float4 xv = *(const float4*)(xp + (size_t)r * E_ + (EBASE));    \
            acc0[r] = fmaf(xv.x, W0[0], acc0[r]);                           \
            acc0[r] = fmaf(xv.y, W0[1], acc0[r]);                           \
            acc0[r] = fmaf(xv.z, W0[2], acc0[r]);                           \
            acc0[r] = fmaf(xv.w, W0[3], acc0[r]);                           \
            acc1[r] = fmaf(xv.x, W1[0], acc1[r]);                           \
            acc1[r] = fmaf(xv.y, W1[1], acc1[r]);                           \
            acc1[r] = fmaf(xv.z, W1[2], acc1[r]);                           \
            acc1[r] = fmaf(xv.w, W1[3], acc1[r]);                           \
        }                                                                   \
        _Pragma("unroll")                                                   \
        for (int u = 0; u < 4; u++) { W0[u] = n0[u]; W1[u] = n1[u]; }       \
    }

    // A/B 2-deep pipeline over 4-e groups: 205 groups (0..204)
    float wa0[4], wa1[4], wb0[4], wb1[4];
#pragma unroll
    for (int u = 0; u < 4; u++) {
        wa0[u] = wp0[(size_t)u * E_];       wa1[u] = wp1[(size_t)u * E_];
        wb0[u] = wp0[(size_t)(4 + u) * E_]; wb1[u] = wp1[(size_t)(4 + u) * E_];
    }
    for (int g = 0; g < 204; g += 2) {         // processes groups 0..203
        PROJ_GROUP(wa0, wa1, g * 4, g + 2)
        PROJ_GROUP(wb0, wb1, (g + 1) * 4, g + 3)
    }
    PROJ_GROUP(wa0, wa1, 816, 204)             // final group 204 (prefetch clamped)
#undef PROJ_GROUP

    {
        const int h = c0 / D_, d = c0 - h * D_;
#pragma unroll
        for (int r = 0; r < 8; r++)
            outp[((size_t)h * L_ + row0 + r) * D_ + d] = acc0[r];
    }
    if (a1) {
        const int h = c1 / D_, d = c1 - h * D_;
#pragma unroll
        for (int r = 0; r < 8; r++)
            outp[((size_t)h * L_ + row0 + r) * D_ + d] = acc1[r];
    }
}

// ================= K2 v2: compression MLP, K+V fused, w1 staged in LDS ==========
// grid (H_*LC_/4, 2), block 256 (4 waves, one row each). y=0: K path (src k32,
// write kcT fp32 [h][44][512] + k16 bf16). y=1: V path (src v32, write vcF bf16
// MFMA-frag order). Same per-output FMA order as before (w1 values identical,
// just read from an LDS copy) -> bit-identical outputs. LDS 27.9 KB.
__global__ __launch_bounds__(256) void k_cmlp(
    const float* __restrict__ k32, const float* __restrict__ v32,
    const float* __restrict__ w1, const float* __restrict__ b1,
    const float* __restrict__ w2, const float* __restrict__ b2,
    float* __restrict__ dstcTk, bfu* __restrict__ dst16, bfu* __restrict__ dstcF)
{
    __shared__ float in_s[4][CB_ * D_];          // 4,592 B
    __shared__ float h_s[4][20];                 //   320 B
    __shared__ float w1s[CB_ * D_ * 20];         // 22,960 B
    const int path = blockIdx.y;                 // 0 = K, 1 = V
    const float* src32 = path ? v32 : k32;
    const int tid = threadIdx.x, lane = tid & 63, wave = tid >> 6;
    const int row = blockIdx.x * 4 + wave;            // h*LC_ + c
    const int h = row / LC_, c = row - h * LC_;
    const size_t base = ((size_t)h * L_ + c * CB_) * D_;

    for (int i = tid; i < CB_ * D_ * 20; i += 256) w1s[i] = w1[i];
    for (int i = lane; i < CB_ * D_; i += 64) {
        float fv = src32[base + i];
        in_s[wave][i] = fv;
        if (path == 0) dst16[base + i] = f2b(fv);
    }
    __syncthreads();
    if (lane < 60) {
        const int col = lane % 20, chunk = lane / 20;
        const int i0 = chunk * 96;
        const int i1 = (chunk == 2) ? (CB_ * D_) : (i0 + 96);
        float a = (chunk == 0) ? b1[col] : 0.f;
        for (int i = i0; i < i1; i++) a += in_s[wave][i] * w1s[i * 20 + col];
        float aa = __shfl_down(a, 20);
        float ab = __shfl_down(a, 40);
        if (lane < 20) h_s[wave][lane] = fmaxf(a + aa + ab, 0.f);
    }
    __syncthreads();
    float a = 0.f;
    if (lane < D_) {
        a = b2[lane];
#pragma unroll
        for (int j = 0; j < 20; j++) a += h_s[wave][j] * w2[j * D_ + lane];
    }
    if (path == 0) {
        if (lane < 44)
            dstcTk[((size_t)h * 44 + lane) * LC_ + c] = a;    // lanes 41..43 write 0
    } else {
        if (lane < 48)
            dstcF[((((size_t)h * 16 + (c >> 5)) * 3 + (lane >> 4)) * 64
                   + (((c >> 3) & 3) * 16 + (lane & 15))) * 8 + (c & 7)] = f2b(a);
    }
}

// ================= K3 v9: compressed attention, key-split waves ==================
// grid (QB_, H_), block 256, 2 passes of 16 q. Wave w owns keys [w*128, w*128+128)
// for ALL 16 q (no kc read duplication). kc read direct from global kc^T —
// COALESCED (64 lanes consecutive fp32). Q staged transposed in LDS. Softmax
// max/sum combined across waves exactly via tiny LDS buffers. PV: MFMA, B-frags
// coalesced from frag-ordered vcF. LDS 20.7 KB; launch_bounds(256,6) -> 6 blk/CU.
__global__ __launch_bounds__(256, 6) void k_comp(
    const float* __restrict__ q32, const float* __restrict__ kcT,
    const bfu* __restrict__ vcF, const float* __restrict__ wg,
    const float* __restrict__ bg, float* __restrict__ outp,
    double* __restrict__ bscore, float* __restrict__ bsp, int b)
{
    __shared__ __align__(16) char scr[16640];      // p_s [16][520] bfu  U  red [4][768] f32
    __shared__ __align__(16) float q_sT[44][20];   // transposed q, rows 41..43 zero
    __shared__ __align__(16) float m_buf[4][16];
    __shared__ __align__(16) float l_buf[4][16];
    __shared__ float g0_s[16];
    const int qb = blockIdx.x, h = blockIdx.y;
    const int tid = threadIdx.x, lane = tid & 63, w = tid >> 6;
    bfu* p_s = (bfu*)scr;
    float* red = (float*)scr;
    const float* kc0 = kcT + (size_t)h * 44 * LC_ + w * 128 + lane;
    const bfu* vf = vcF + (size_t)h * 16 * 3 * 64 * 8;
    const int lrow = lane & 15, lgr = lane >> 4;

    float bs0 = 0.f, bs1 = 0.f;   // block-score partials for keys w*128+lane, +64

#pragma unroll 1
    for (int pass = 0; pass < 2; pass++) {
        const int q0 = qb * 32 + pass * 16;
        // ---- stage q transposed (coalesced global reads) ----
        for (int i = tid; i < 16 * 44; i += 256) {
            int qq = i / 44, d = i - qq * 44;
            q_sT[d][qq] = (d < D_) ? q32[((size_t)h * L_ + q0 + qq) * D_ + d] : 0.f;
        }
        __syncthreads();

        if (tid < 16) {   // gates (fp32)
            float a0 = bg[0], a1g = bg[1], a2 = bg[2];
            for (int d = 0; d < D_; d++) {
                float qd = q_sT[d][tid];
                a0  += qd * wg[d * 3 + 0];
                a1g += qd * wg[d * 3 + 1];
                a2  += qd * wg[d * 3 + 2];
            }
            float gm = fmaxf(a0, fmaxf(a1g, a2));
            float e0 = __expf(a0 - gm), e1 = __expf(a1g - gm), e2 = __expf(a2 - gm);
            g0_s[tid] = e0 / (e0 + e1 + e2);
        }

        // ---- scores: s0/s1[q] for keys w*128+lane, w*128+64+lane ----
        float s0[16], s1[16];
#pragma unroll
        for (int j = 0; j < 16; j++) { s0[j] = 0.f; s1[j] = 0.f; }

        for (int d = 0; d < 44; d++) {
            float kv0 = kc0[(size_t)d * LC_];        // coalesced 256B wave-load
            float kv1 = kc0[(size_t)d * LC_ + 64];
            float4 qa = *(const float4*)&q_sT[d][0];
            float4 qbv = *(const float4*)&q_sT[d][4];
            float4 qc = *(const float4*)&q_sT[d][8];
            float4 qd = *(const float4*)&q_sT[d][12];
            s0[0]  = fmaf(qa.x,  kv0, s0[0]);  s1[0]  = fmaf(qa.x,  kv1, s1[0]);
            s0[1]  = fmaf(qa.y,  kv0, s0[1]);  s1[1]  = fmaf(qa.y,  kv1, s1[1]);
            s0[2]  = fmaf(qa.z,  kv0, s0[2]);  s1[2]  = fmaf(qa.z,  kv1, s1[2]);
            s0[3]  = fmaf(qa.w,  kv0, s0[3]);  s1[3]  = fmaf(qa.w,  kv1, s1[3]);
            s0[4]  = fmaf(qbv.x, kv0, s0[4]);  s1[4]  = fmaf(qbv.x, kv1, s1[4]);
            s0[5]  = fmaf(qbv.y, kv0, s0[5]);  s1[5]  = fmaf(qbv.y, kv1, s1[5]);
            s0[6]  = fmaf(qbv.z, kv0, s0[6]);  s1[6]  = fmaf(qbv.z, kv1, s1[6]);
            s0[7]  = fmaf(qbv.w, kv0, s0[7]);  s1[7]  = fmaf(qbv.w, kv1, s1[7]);
            s0[8]  = fmaf(qc.x,  kv0, s0[8]);  s1[8]  = fmaf(qc.x,  kv1, s1[8]);
            s0[9]  = fmaf(qc.y,  kv0, s0[9]);  s1[9]  = fmaf(qc.y,  kv1, s1[9]);
            s0[10] = fmaf(qc.z,  kv0, s0[10]); s1[10] = fmaf(qc.z,  kv1, s1[10]);
            s0[11] = fmaf(qc.w,  kv0, s0[11]); s1[11] = fmaf(qc.w,  kv1, s1[11]);
            s0[12] = fmaf(qd.x,  kv0, s0[12]); s1[12] = fmaf(qd.x,  kv1, s1[12]);
            s0[13] = fmaf(qd.y,  kv0, s0[13]); s1[13] = fmaf(qd.y,  kv1, s1[13]);
            s0[14] = fmaf(qd.z,  kv0, s0[14]); s1[14] = fmaf(qd.z,  kv1, s1[14]);
            s0[15] = fmaf(qd.w,  kv0, s0[15]); s1[15] = fmaf(qd.w,  kv1, s1[15]);
        }

        // ---- softmax: exact max (order-invariant), cross-wave via LDS ----
#pragma unroll
        for (int j = 0; j < 16; j++) {
            s0[j] *= SCALE; s1[j] *= SCALE;
            float m = fmaxf(s0[j], s1[j]);
            for (int o = 32; o; o >>= 1) m = fmaxf(m, __shfl_xor(m, o));
            if (lane == 0) m_buf[w][j] = m;
        }
        __syncthreads();
#pragma unroll
        for (int jq = 0; jq < 4; jq++) {
            float4 m0 = *(const float4*)&m_buf[0][jq * 4];
            float4 m1 = *(const float4*)&m_buf[1][jq * 4];
            float4 m2 = *(const float4*)&m_buf[2][jq * 4];
            float4 m3 = *(const float4*)&m_buf[3][jq * 4];
            float4 mg;
            mg.x = fmaxf(fmaxf(m0.x, m1.x), fmaxf(m2.x, m3.x));
            mg.y = fmaxf(fmaxf(m0.y, m1.y), fmaxf(m2.y, m3.y));
            mg.z = fmaxf(fmaxf(m0.z, m1.z), fmaxf(m2.z, m3.z));
            mg.w = fmaxf(fmaxf(m0.w, m1.w), fmaxf(m2.w, m3.w));
#pragma unroll
            for (int j2 = 0; j2 < 4; j2++) {
                const int j = jq * 4 + j2;
                const float mgv = (j2 == 0) ? mg.x : (j2 == 1) ? mg.y : (j2 == 2) ? mg.z : mg.w;
                float e0 = expf(s0[j] - mgv);
                float e1 = expf(s1[j] - mgv);
                s0[j] = e0; s1[j] = e1;
                float ls = e0 + e1;
                for (int o = 32; o; o >>= 1) ls += __shfl_xor(ls, o);
                if (lane == 0) l_buf[w][j] = ls;
            }
        }
        __syncthreads();
#pragma unroll
        for (int jq = 0; jq < 4; jq++) {
            float4 l0 = *(const float4*)&l_buf[0][jq * 4];
            float4 l1 = *(const float4*)&l_buf[1][jq * 4];
            float4 l2 = *(const float4*)&l_buf[2][jq * 4];
            float4 l3 = *(const float4*)&l_buf[3][jq * 4];
            float4 lt;
            lt.x = l0.x + l1.x + l2.x + l3.x;
            lt.y = l0.y + l1.y + l2.y + l3.y;
            lt.z = l0.z + l1.z + l2.z + l3.z;
            lt.w = l0.w + l1.w + l2.w + l3.w;
#pragma unroll
            for (int j2 = 0; j2 < 4; j2++) {
                const int j = jq * 4 + j2;
                const float ltv = (j2 == 0) ? lt.x : (j2 == 1) ? lt.y : (j2 == 2) ? lt.z : lt.w;
                const float inv = 1.f / ltv;
                float p0 = s0[j] * inv;
                float p1 = s1[j] * inv;
                p_s[j * 520 + w * 128 + lane]      = f2b(p0);
                p_s[j * 520 + w * 128 + 64 + lane] = f2b(p1);
                bs0 += p0; bs1 += p1;
            }
        }
        // wave's PV reads only its OWN p_s columns -> no barrier needed here

        // ---- PV via MFMA: wave w covers k-range [w*128, w*128+128) ----
        f32x4 acc[3];
#pragma unroll
        for (int nt = 0; nt < 3; nt++) acc[nt] = (f32x4){0.f, 0.f, 0.f, 0.f};
#pragma unroll
        for (int ks = 0; ks < 4; ks++) {
            const int k0 = w * 128 + ks * 32;
            bf16x8 av = *(const bf16x8*)&p_s[lrow * 520 + k0 + lgr * 8];
#pragma unroll
            for (int nt = 0; nt < 3; nt++) {
                bf16x8 bv = *(const bf16x8*)&vf[(((size_t)(w * 4 + ks) * 3 + nt) * 64 + lane) * 8];
                acc[nt] = __builtin_amdgcn_mfma_f32_16x16x32_bf16(av, bv, acc[nt], 0, 0, 0);
            }
        }
        __syncthreads();   // all PV p_s reads done before red overlays p_s

        // ---- cross-wave k-reduction (red overlays p_s) ----
#pragma unroll
        for (int nt = 0; nt < 3; nt++)
#pragma unroll
            for (int r = 0; r < 4; r++)
                red[w * 768 + (nt * 4 + r) * 64 + lane] = acc[nt][r];
        __syncthreads();
        for (int i = tid; i < 16 * 48; i += 256) {
            int q = i / 48, d = i - q * 48;
            if (d < D_) {
                int lg = q >> 2, r = q & 3, nt = d >> 4, lr = d & 15;
                int fi = (nt * 4 + r) * 64 + lg * 16 + lr;
                float v = red[fi] + red[768 + fi] + red[1536 + fi] + red[2304 + fi];
                outp[((size_t)(b * L_ + q0 + q)) * (H_ * D_) + h * D_ + d] = g0_s[q] * v;
            }
        }
        __syncthreads();   // red/q_sT dead before next pass
    }

    // ---- block scores: thread owns keys w*128+lane, +64 exclusively ----
    const int j0 = w * 128 + lane;
    if (bsp) {
        float* bp = &bsp[((size_t)h * QB_ + qb) * LC_];
        bp[j0] = bs0;
        bp[j0 + 64] = bs1;
    } else {
        double* bqd = &bscore[((size_t)(qb & (NREP_ - 1)) * H_ + h) * LC_];
        atomicAdd(&bqd[j0], (double)bs0);
        atomicAdd(&bqd[j0 + 64], (double)bs1);
    }
}

// ================= K4: top-k (per batch; fp32 partials or replicated fp64) ==
// grid 20, block 64
__global__ __launch_bounds__(64) void k_topk(const double* __restrict__ bs,
                                             const float* __restrict__ bsp,
                                             int* __restrict__ idxo)
{
    __shared__ double vb_[64];
    __shared__ int ib_[64];
    __shared__ int win;
    const int h = blockIdx.x, lane = threadIdx.x;
    double vals[8];
    if (bsp) {   // deterministic sequential fp64 sum of the 112 fp32 per-block partials
#pragma unroll
        for (int r = 0; r < 8; r++) vals[r] = 0.0;
        for (int pb = 0; pb < QB_; pb++) {
            const float* rowp = &bsp[((size_t)h * QB_ + pb) * LC_];
#pragma unroll
            for (int r = 0; r < 8; r++) vals[r] += (double)rowp[r * 64 + lane];
        }
    } else {     // sum the NREP_ fp64 replicas
#pragma unroll
        for (int r = 0; r < 8; r++) {
            int j = r * 64 + lane;
            double v = 0.0;
#pragma unroll
            for (int rep = 0; rep < NREP_; rep++)
                v += bs[((size_t)rep * H_ + h) * LC_ + j];
            vals[r] = v;
        }
    }
    for (int t = 0; t < TOPK_; t++) {
        double bv = -1e30; int bi = 0x7fffffff;
#pragma unroll
        for (int r = 0; r < 8; r++) {
            int j = r * 64 + lane;
            bool better = (vals[r] > bv) || (vals[r] == bv && j < bi);
            if (better) { bv = vals[r]; bi = j; }
        }
        vb_[lane] = bv; ib_[lane] = bi;
        __syncthreads();
        if (lane == 0) {
            double best = -1e30; int besti = 0x7fffffff;
            for (int u = 0; u < 64; u++) {
                if (vb_[u] > best || (vb_[u] == best && ib_[u] < besti)) { best = vb_[u]; besti = ib_[u]; }
            }
            idxo[h * TOPK_ + t] = besti;
            win = besti;
        }
        __syncthreads();
        int w = win;
#pragma unroll
        for (int r = 0; r < 8; r++)
            if ((w >> 6) == r && (w & 63) == lane) vals[r] = -1e30;
        __syncthreads();
    }
}

// ================= K5 v3: selected + window attention, 32 queries/block ==============
// grid (QB_, 20), block 256. Wave owns 8 queries in 2 groups of 4.
__global__ __launch_bounds__(256) void k_selwin(
    const float* __restrict__ q32, const bfu* __restrict__ k16,
    const float* __restrict__ v32, const int* __restrict__ idxp,
    const float* __restrict__ wg, const float* __restrict__ bg,
    float* __restrict__ outp, int b)
{
    __shared__ __align__(16) bfu ks_s[119][44];      // 112 sel + 7 window keys
    __shared__ __align__(16) float vsT[D_][130];     // fp32 v^T, pad 130
    __shared__ __align__(16) float q_s[32][44];
    __shared__ __align__(16) bfu p_s[32][NSEL_];
    __shared__ int rows_s[NSEL_];
    __shared__ float g1_s[32];
    __shared__ float pw_s[32][CB_];                  // g2-scaled window probs
    const int h = blockIdx.y;
    const int q0 = blockIdx.x * 32;
    const int tid = threadIdx.x, lane = tid & 63, wave = tid >> 6;
    const size_t kvbase = (size_t)h * L_ * D_;

    for (int i = tid; i < 32 * D_; i += 256) {
        int qq = i / D_, d = i - qq * D_;
        q_s[qq][d] = q32[((size_t)h * L_ + q0 + qq) * D_ + d];
    }
    if (tid < NSEL_) {
        int t = tid / CB_;
        rows_s[tid] = idxp[h * TOPK_ + t] * CB_ + (tid - t * CB_);
    }
    __syncthreads();

    for (int i = tid; i < 119 * D_; i += 256) {
        int key = i / D_, d = i - key * D_;
        int row = (key < NSEL_) ? rows_s[key] : (L_ - CB_ + (key - NSEL_));
        ks_s[key][d] = k16[kvbase + (size_t)row * D_ + d];
        vsT[d][key]  = v32[kvbase + (size_t)row * D_ + d];
    }
    __syncthreads();

    if (tid < 32) {   // gates + window softmax (x g2)
        float a0 = bg[0], a1 = bg[1], a2 = bg[2];
        for (int d = 0; d < D_; d++) {
            float qd = q_s[tid][d];
            a0 += qd * wg[d * 3 + 0];
            a1 += qd * wg[d * 3 + 1];
            a2 += qd * wg[d * 3 + 2];
        }
        float gm = fmaxf(a0, fmaxf(a1, a2));
        float e0 = __expf(a0 - gm), e1 = __expf(a1 - gm), e2 = __expf(a2 - gm);
        float ginv = 1.f / (e0 + e1 + e2);
        g1_s[tid] = e1 * ginv;
        float g2 = e2 * ginv;
        float sw[CB_];
        float m = -1e30f;
        for (int i = 0; i < CB_; i++) {
            float ss = 0.f;
            for (int d = 0; d < D_; d++) ss += q_s[tid][d] * b2f(ks_s[NSEL_ + i][d]);
            sw[i] = ss * SCALE;
            m = fmaxf(m, sw[i]);
        }
        float lsum = 0.f;
        for (int i = 0; i < CB_; i++) { sw[i] = __expf(sw[i] - m); lsum += sw[i]; }
        float winv = g2 / lsum;
        for (int i = 0; i < CB_; i++) pw_s[tid][i] = sw[i] * winv;
    }
    __syncthreads();

    const bool v1 = (64 + lane) < NSEL_;
    const int row1c = v1 ? (64 + lane) : 0;
    for (int g = 0; g < 2; g++) {
        const int qb2 = wave * 8 + g * 4;
        float s0[4] = {0, 0, 0, 0}, s1[4] = {0, 0, 0, 0};
        for (int dc = 0; dc < 10; dc++) {
            float4 qv[4];
#pragma unroll
            for (int qi = 0; qi < 4; qi++) qv[qi] = *(const float4*)&q_s[qb2 + qi][dc * 4];
            uint2 ra = *(const uint2*)&ks_s[lane][dc * 4];
            uint2 rb = *(const uint2*)&ks_s[row1c][dc * 4];
            float a0, a1, a2, a3, c0, c1, c2, c3;
            b2x2(ra.x, a0, a1); b2x2(ra.y, a2, a3);
            b2x2(rb.x, c0, c1); b2x2(rb.y, c2, c3);
#pragma unroll
            for (int qi = 0; qi < 4; qi++) {
                s0[qi] += qv[qi].x * a0 + qv[qi].y * a1 + qv[qi].z * a2 + qv[qi].w * a3;
                s1[qi] += qv[qi].x * c0 + qv[qi].y * c1 + qv[qi].z * c2 + qv[qi].w * c3;
            }
        }
        {
            float ka = b2f(ks_s[lane][40]);
            float kb = b2f(ks_s[row1c][40]);
#pragma unroll
            for (int qi = 0; qi < 4; qi++) {
                float qt = q_s[qb2 + qi][40];
                s0[qi] += qt * ka; s1[qi] += qt * kb;
            }
        }
#pragma unroll
        for (int qi = 0; qi < 4; qi++) {
            float a0 = s0[qi] * SCALE;
            float a1 = v1 ? s1[qi] * SCALE : -1e30f;
            float m = fmaxf(a0, a1);
            for (int o = 32; o; o >>= 1) m = fmaxf(m, __shfl_xor(m, o));
            float e0 = __expf(a0 - m);
            float e1 = v1 ? __expf(a1 - m) : 0.f;
            float lsum = e0 + e1;
            for (int o = 32; o; o >>= 1) lsum += __shfl_xor(lsum, o);
            float inv = 1.f / lsum;
            p_s[qb2 + qi][lane] = f2b(e0 * inv);
            if (v1) p_s[qb2 + qi][64 + lane] = f2b(e1 * inv);
        }
    }
    __syncthreads();

    if (lane < D_) {
        for (int g = 0; g < 2; g++) {
            const int qb2 = wave * 8 + g * 4;
            float acc[4] = {0, 0, 0, 0};
            for (int jc = 0; jc < NSEL_; jc += 4) {
                float2 va = *(const float2*)&vsT[lane][jc];
                float2 vb = *(const float2*)&vsT[lane][jc + 2];
#pragma unroll
                for (int qi = 0; qi < 4; qi++) {
                    uint2 pp = *(const uint2*)&p_s[qb2 + qi][jc];
                    float p0, p1, p2, p3;
                    b2x2(pp.x, p0, p1); b2x2(pp.y, p2, p3);
                    acc[qi] += p0 * va.x + p1 * va.y + p2 * vb.x + p3 * vb.y;
                }
            }
#pragma unroll
            for (int qi = 0; qi < 4; qi++) {
                int row = qb2 + qi;
                float wvv = 0.f;
#pragma unroll
                for (int i = 0; i < CB_; i++) wvv += pw_s[row][i] * vsT[lane][NSEL_ + i];
                float* op = &outp[((size_t)(b * L_ + q0 + row)) * (H_ * D_) + h * D_ + lane];
                *op = *op + g1_s[row] * acc[qi] + wvv;
            }
        }
    }
}

extern "C" void kernel_launch(void* const* d_in, const int* in_sizes, int n_in,
                              void* d_out, int out_size, void* d_ws, size_t ws_size,
                              hipStream_t stream) {
    (void)in_sizes; (void)n_in;
    const float* x  = (const float*)d_in[0];
    const float* wq = (const float*)d_in[1];  const float* bq = (const float*)d_in[2];
    const float* wk = (const float*)d_in[3];  const float* bk = (const float*)d_in[4];
    const float* wv = (const float*)d_in[5];  const float* bv = (const float*)d_in[6];
    const float* w1 = (const float*)d_in[7];  const float* b1 = (const float*)d_in[8];
    const float* w2 = (const float*)d_in[9];  const float* b2 = (const float*)d_in[10];
    const float* wg = (const float*)d_in[11]; const float* bg = (const float*)d_in[12];

    if (d_ws == nullptr || ws_size < WS_NEEDED) {
        k_fail<<<dim3((out_size + 255) / 256), 256, 0, stream>>>((float*)d_out, out_size);
        return;
    }

    char* ws = (char*)d_ws;
    float*  r1   = (float*)(ws + OFF_R1);    // k32 then q32
    float*  v32  = (float*)(ws + OFF_V32);
    bfu*    k16  = (bfu*)(ws + OFF_K16);
    float*  kcT  = (float*)(ws + OFF_KCT);
    bfu*    vcF  = (bfu*)(ws + OFF_VCF);
    double* bsc  = (double*)(ws + OFF_BS);
    int*    idxp = (int*)(ws + OFF_IDX);
    float*  outp = (float*)d_out;
    // atomic-free block-score partials if workspace allows (else replicated fp64 atomics)
    const bool big = (ws_size >= WS_BIG);
    float*  bsp  = big ? (float*)(ws + OFF_BSP) : (float*)nullptr;

    for (int b = 0; b < B_; b++) {
        if (!big)
            k_zero_d<<<dim3((NREP_ * H_ * LC_ + 255) / 256), 256, 0, stream>>>(bsc, NREP_ * H_ * LC_);
        // K -> r1 and V -> v32 in one fused launch
        k_proj2<<<dim3(L_ / 8, 2, 2), 256, 0, stream>>>(x, wk, bk, r1, wv, bv, v32, b);
        // fused compression MLP: y=0 K path (kcT + k16 from r1), y=1 V path (vcF from v32)
        k_cmlp<<<dim3(H_ * LC_ / 4, 2), 256, 0, stream>>>(r1, v32, w1, b1, w2, b2, kcT, k16, vcF);
        // Q -> r1 (overwrites k32; cmlp K path done)
        k_proj2<<<dim3(L_ / 8, 2, 1), 256, 0, stream>>>(x, wq, bq, r1, wq, bq, r1, b);
        k_comp<<<dim3(QB_, H_), 256, 0, stream>>>(r1, kcT, vcF, wg, bg, outp, bsc, bsp, b);
        k_topk<<<dim3(H_), 64, 0, stream>>>(bsc, bsp, idxp);
        k_selwin<<<dim3(QB_, H_), 256, 0, stream>>>(r1, k16, v32, idxp, wg, bg, outp, b);
    }
}

// Round 11
// 1519.738 us; speedup vs baseline: 1.3956x; 1.0004x over previous
//
#include <hip/hip_runtime.h>

#define B_ 2
#define L_ 3584
#define E_ 820
#define H_ 20
#define D_ 41
#define CB_ 7
#define LC_ 512      // L_/CB_
#define TOPK_ 16
#define NSEL_ 112    // TOPK_*CB_
#define QB_ 112      // L_/32 query-blocks per head
#define NREP_ 4      // fp64 score replicas (fallback path)
#define SCALE 0.15617376188860607f  // 1/sqrt(41)

typedef unsigned short bfu;
typedef __attribute__((ext_vector_type(8))) short bf16x8;   // 8 bf16 (4 VGPRs)
typedef __attribute__((ext_vector_type(4))) float f32x4;    // MFMA C/D

__device__ __forceinline__ float b2f(bfu h) {
    union { unsigned u; float f; } c; c.u = ((unsigned)h) << 16; return c.f;
}
__device__ __forceinline__ bfu f2b(float f) {
    union { float f; unsigned u; } c; c.f = f;
    unsigned u = c.u;
    return (bfu)((u + 0x7fffu + ((u >> 16) & 1u)) >> 16);
}
__device__ __forceinline__ void b2x2(unsigned u, float& a, float& b) {
    union { unsigned u; float f; } c0, c1;
    c0.u = u << 16; c1.u = u & 0xffff0000u;
    a = c0.f; b = c1.f;
}

// ---------------- workspace layout (bytes) — per-batch reuse ----------------
#define NHLD ((size_t)H_ * L_ * D_)
#define OFF_R1   ((size_t)0)                          // fp32 (k32 then q32)
#define OFF_V32  (OFF_R1  + NHLD * 4)                 // fp32 V
#define OFF_K16  (OFF_V32 + NHLD * 4)                 // bf16 K
#define OFF_KCT  (OFF_K16 + NHLD * 2)                 // fp32 kc^T [H][44][512]
#define OFF_VCF  (OFF_KCT + (size_t)H_ * 44 * LC_ * 4)   // bf16 vc frag [H][16][3][64][8]
#define OFF_BS   (OFF_VCF + (size_t)H_ * 16 * 3 * 64 * 8 * 2)  // fp64 x NREP_ (fallback)
#define OFF_IDX  (OFF_BS  + (size_t)NREP_ * H_ * LC_ * 8)
#define WS_NEEDED (OFF_IDX + (size_t)H_ * TOPK_ * 4)  // 32,503,040 <= proven 32,830,720
// optional extension: per-block fp32 block-score partials [H][QB_][LC_]
#define OFF_BSP  WS_NEEDED
#define WS_BIG   (OFF_BSP + (size_t)H_ * QB_ * LC_ * 4)

// ================= K-fail =================
__global__ __launch_bounds__(256) void k_fail(float* __restrict__ out, int n) {
    int i = blockIdx.x * 256 + threadIdx.x;
    if (i < n) out[i] = 0.f;
}

// ================= K0: zero block scores (double, atomic-fallback mode only) ==
__global__ __launch_bounds__(256) void k_zero_d(double* __restrict__ p, int n) {
    int i = blockIdx.x * 256 + threadIdx.x;
    if (i < n) p[i] = 0.0;
}

// ================= K1 v9: NO-LDS scalar-x proj + wave-uniform dual/single split ==
// grid (448, 2, nz), block 256. 8 rows x 512 cols per block, 2 cols/thread.
// Waves whose ENTIRE c1 range is >= E_ (waves 1-3 of y=1 blocks) run a
// single-column pipeline: half the FMAs, half the w-loads — removes the 18.75%
// of FMA work the col-pad was discarding. All other waves run the round-7
// proven dual pipeline unchanged. Outputs bit-identical (per-column e-order
// 0..819 ascending, 4 at a time; dead columns were never stored).
__global__ __launch_bounds__(256) void k_proj2(
    const float* __restrict__ x,
    const float* __restrict__ wA, const float* __restrict__ bA, float* __restrict__ outA,
    const float* __restrict__ wB, const float* __restrict__ bB, float* __restrict__ outB,
    int b)
{
    const float* w    = (blockIdx.z == 0) ? wA : wB;
    const float* bias = (blockIdx.z == 0) ? bA : bB;
    float* outp       = (blockIdx.z == 0) ? outA : outB;
    const int row0 = blockIdx.x * 8;
    const int c0 = blockIdx.y * 512 + threadIdx.x;   // always < 820
    const int c1 = c0 + 256;
    const bool a1 = (c1 < E_);
    const int cc1 = a1 ? c1 : (E_ - 1);
    // wave-uniform: true when the whole wave's c1 range is out of bounds
    const bool singlew = ((blockIdx.y * 512 + (threadIdx.x & ~63)) + 256) >= E_;
    float acc0[8], acc1[8];
    const float bb0 = bias[c0];
    const float bb1 = bias[cc1];
#pragma unroll
    for (int r = 0; r < 8; r++) { acc0[r] = bb0; acc1[r] = bb1; }

    const float* xp  = x + ((size_t)b * L_ + row0) * E_;  // uniform row-block base
    const float* wp0 = w + c0;
    const float* wp1 = w + cc1;

#define PROJ_GROUP(W0, W1, EBASE, PREFG)                                    \
    {                                                                       \
        float n0[4], n1[4];                                                 \
        const int pg = ((PREFG) < 204) ? (PREFG) : 204;                     \
        _Pragma("unroll")                                                   \
        for (int u = 0; u < 4; u++) {                                       \
            n0[u] = wp0[(size_t)(pg * 4 + u) * E_];                         \
            n1[u] = wp1[(size_t)(pg * 4 + u) * E_];                         \
        }                                                                   \
        _Pragma("unroll")                                                   \
        for (int r = 0; r < 8; r++) {                                       \
            float4 xv = *(const float4*)(xp + (size_t)r * E_ + (EBASE));    \
            acc0[r] = fmaf(xv.x, W0[0], acc0[r]);                           \
            acc0[r] = fmaf(xv.y, W0[1], acc0[r]);                           \
            acc0[r] = fmaf(xv.z, W0[2], acc0[r]);                           \
            acc0[r] = fmaf(xv.w, W0[3], acc0[r]);                           \
            acc1[r] = fmaf(xv.x, W1[0], acc1[r]);                           \
            acc1[r] = fmaf(xv.y, W1[1], acc1[r]);                           \
            acc1[r] = fmaf(xv.z, W1[2], acc1[r]);                           \
            acc1[r] = fmaf(xv.w, W1[3], acc1[r]);                           \
        }                                                                   \
        _Pragma("unroll")                                                   \
        for (int u = 0; u < 4; u++) { W0[u] = n0[u]; W1[u] = n1[u]; }       \
    }

#define PROJ_GROUP1(W0, EBASE, PREFG)                                       \
    {                                                                       \
        float n0[4];                                                        \
        const int pg = ((PREFG) < 204) ? (PREFG) : 204;                     \
        _Pragma("unroll")                                                   \
        for (int u = 0; u < 4; u++)                                         \
            n0[u] = wp0[(size_t)(pg * 4 + u) * E_];                         \
        _Pragma("unroll")                                                   \
        for (int r = 0; r < 8; r++) {                                       \
            float4 xv = *(const float4*)(xp + (size_t)r * E_ + (EBASE));    \
            acc0[r] = fmaf(xv.x, W0[0], acc0[r]);                           \
            acc0[r] = fmaf(xv.y, W0[1], acc0[r]);                           \
            acc0[r] = fmaf(xv.z, W0[2], acc0[r]);                           \
            acc0[r] = fmaf(xv.w, W0[3], acc0[r]);                           \
        }                                                                   \
        _Pragma("unroll")                                                   \
        for (int u = 0; u < 4; u++) { W0[u] = n0[u]; }                      \
    }

    if (!singlew) {
        // ---- dual-column pipeline (round-7 proven path, unchanged) ----
        float wa0[4], wa1[4], wb0[4], wb1[4];
#pragma unroll
        for (int u = 0; u < 4; u++) {
            wa0[u] = wp0[(size_t)u * E_];       wa1[u] = wp1[(size_t)u * E_];
            wb0[u] = wp0[(size_t)(4 + u) * E_]; wb1[u] = wp1[(size_t)(4 + u) * E_];
        }
        for (int g = 0; g < 204; g += 2) {         // processes groups 0..203
            PROJ_GROUP(wa0, wa1, g * 4, g + 2)
            PROJ_GROUP(wb0, wb1, (g + 1) * 4, g + 3)
        }
        PROJ_GROUP(wa0, wa1, 816, 204)             // final group 204
    } else {
        // ---- single-column pipeline (c1 dead for every lane of this wave) ----
        float wa0[4], wb0[4];
#pragma unroll
        for (int u = 0; u < 4; u++) {
            wa0[u] = wp0[(size_t)u * E_];
            wb0[u] = wp0[(size_t)(4 + u) * E_];
        }
        for (int g = 0; g < 204; g += 2) {
            PROJ_GROUP1(wa0, g * 4, g + 2)
            PROJ_GROUP1(wb0, (g + 1) * 4, g + 3)
        }
        PROJ_GROUP1(wa0, 816, 204)
    }
#undef PROJ_GROUP
#undef PROJ_GROUP1

    {
        const int h = c0 / D_, d = c0 - h * D_;
#pragma unroll
        for (int r = 0; r < 8; r++)
            outp[((size_t)h * L_ + row0 + r) * D_ + d] = acc0[r];
    }
    if (a1) {
        const int h = c1 / D_, d = c1 - h * D_;
#pragma unroll
        for (int r = 0; r < 8; r++)
            outp[((size_t)h * L_ + row0 + r) * D_ + d] = acc1[r];
    }
}

// ================= K2 v2: compression MLP, K+V fused, w1 staged in LDS ==========
// grid (H_*LC_/4, 2), block 256 (4 waves, one row each). y=0: K path (src k32,
// write kcT fp32 [h][44][512] + k16 bf16). y=1: V path (src v32, write vcF bf16
// MFMA-frag order). Bit-identical outputs. LDS 27.9 KB.
__global__ __launch_bounds__(256) void k_cmlp(
    const float* __restrict__ k32, const float* __restrict__ v32,
    const float* __restrict__ w1, const float* __restrict__ b1,
    const float* __restrict__ w2, const float* __restrict__ b2,
    float* __restrict__ dstcTk, bfu* __restrict__ dst16, bfu* __restrict__ dstcF)
{
    __shared__ float in_s[4][CB_ * D_];          // 4,592 B
    __shared__ float h_s[4][20];                 //   320 B
    __shared__ float w1s[CB_ * D_ * 20];         // 22,960 B
    const int path = blockIdx.y;                 // 0 = K, 1 = V
    const float* src32 = path ? v32 : k32;
    const int tid = threadIdx.x, lane = tid & 63, wave = tid >> 6;
    const int row = blockIdx.x * 4 + wave;            // h*LC_ + c
    const int h = row / LC_, c = row - h * LC_;
    const size_t base = ((size_t)h * L_ + c * CB_) * D_;

    for (int i = tid; i < CB_ * D_ * 20; i += 256) w1s[i] = w1[i];
    for (int i = lane; i < CB_ * D_; i += 64) {
        float fv = src32[base + i];
        in_s[wave][i] = fv;
        if (path == 0) dst16[base + i] = f2b(fv);
    }
    __syncthreads();
    if (lane < 60) {
        const int col = lane % 20, chunk = lane / 20;
        const int i0 = chunk * 96;
        const int i1 = (chunk == 2) ? (CB_ * D_) : (i0 + 96);
        float a = (chunk == 0) ? b1[col] : 0.f;
        for (int i = i0; i < i1; i++) a += in_s[wave][i] * w1s[i * 20 + col];
        float aa = __shfl_down(a, 20);
        float ab = __shfl_down(a, 40);
        if (lane < 20) h_s[wave][lane] = fmaxf(a + aa + ab, 0.f);
    }
    __syncthreads();
    float a = 0.f;
    if (lane < D_) {
        a = b2[lane];
#pragma unroll
        for (int j = 0; j < 20; j++) a += h_s[wave][j] * w2[j * D_ + lane];
    }
    if (path == 0) {
        if (lane < 44)
            dstcTk[((size_t)h * 44 + lane) * LC_ + c] = a;    // lanes 41..43 write 0
    } else {
        if (lane < 48)
            dstcF[((((size_t)h * 16 + (c >> 5)) * 3 + (lane >> 4)) * 64
                   + (((c >> 3) & 3) * 16 + (lane & 15))) * 8 + (c & 7)] = f2b(a);
    }
}

// ================= K3 v9: compressed attention, key-split waves ==================
// grid (QB_, H_), block 256, 2 passes of 16 q. Wave w owns keys [w*128, w*128+128)
// for ALL 16 q (no kc read duplication). kc read direct from global kc^T —
// COALESCED (64 lanes consecutive fp32). Q staged transposed in LDS. Softmax
// max/sum combined across waves exactly via tiny LDS buffers. PV: MFMA, B-frags
// coalesced from frag-ordered vcF. LDS 20.7 KB; launch_bounds(256,6) -> 6 blk/CU.
__global__ __launch_bounds__(256, 6) void k_comp(
    const float* __restrict__ q32, const float* __restrict__ kcT,
    const bfu* __restrict__ vcF, const float* __restrict__ wg,
    const float* __restrict__ bg, float* __restrict__ outp,
    double* __restrict__ bscore, float* __restrict__ bsp, int b)
{
    __shared__ __align__(16) char scr[16640];      // p_s [16][520] bfu  U  red [4][768] f32
    __shared__ __align__(16) float q_sT[44][20];   // transposed q, rows 41..43 zero
    __shared__ __align__(16) float m_buf[4][16];
    __shared__ __align__(16) float l_buf[4][16];
    __shared__ float g0_s[16];
    const int qb = blockIdx.x, h = blockIdx.y;
    const int tid = threadIdx.x, lane = tid & 63, w = tid >> 6;
    bfu* p_s = (bfu*)scr;
    float* red = (float*)scr;
    const float* kc0 = kcT + (size_t)h * 44 * LC_ + w * 128 + lane;
    const bfu* vf = vcF + (size_t)h * 16 * 3 * 64 * 8;
    const int lrow = lane & 15, lgr = lane >> 4;

    float bs0 = 0.f, bs1 = 0.f;   // block-score partials for keys w*128+lane, +64

#pragma unroll 1
    for (int pass = 0; pass < 2; pass++) {
        const int q0 = qb * 32 + pass * 16;
        // ---- stage q transposed (coalesced global reads) ----
        for (int i = tid; i < 16 * 44; i += 256) {
            int qq = i / 44, d = i - qq * 44;
            q_sT[d][qq] = (d < D_) ? q32[((size_t)h * L_ + q0 + qq) * D_ + d] : 0.f;
        }
        __syncthreads();

        if (tid < 16) {   // gates (fp32)
            float a0 = bg[0], a1g = bg[1], a2 = bg[2];
            for (int d = 0; d < D_; d++) {
                float qd = q_sT[d][tid];
                a0  += qd * wg[d * 3 + 0];
                a1g += qd * wg[d * 3 + 1];
                a2  += qd * wg[d * 3 + 2];
            }
            float gm = fmaxf(a0, fmaxf(a1g, a2));
            float e0 = __expf(a0 - gm), e1 = __expf(a1g - gm), e2 = __expf(a2 - gm);
            g0_s[tid] = e0 / (e0 + e1 + e2);
        }

        // ---- scores: s0/s1[q] for keys w*128+lane, w*128+64+lane ----
        float s0[16], s1[16];
#pragma unroll
        for (int j = 0; j < 16; j++) { s0[j] = 0.f; s1[j] = 0.f; }

        for (int d = 0; d < 44; d++) {
            float kv0 = kc0[(size_t)d * LC_];        // coalesced 256B wave-load
            float kv1 = kc0[(size_t)d * LC_ + 64];
            float4 qa = *(const float4*)&q_sT[d][0];
            float4 qbv = *(const float4*)&q_sT[d][4];
            float4 qc = *(const float4*)&q_sT[d][8];
            float4 qd = *(const float4*)&q_sT[d][12];
            s0[0]  = fmaf(qa.x,  kv0, s0[0]);  s1[0]  = fmaf(qa.x,  kv1, s1[0]);
            s0[1]  = fmaf(qa.y,  kv0, s0[1]);  s1[1]  = fmaf(qa.y,  kv1, s1[1]);
            s0[2]  = fmaf(qa.z,  kv0, s0[2]);  s1[2]  = fmaf(qa.z,  kv1, s1[2]);
            s0[3]  = fmaf(qa.w,  kv0, s0[3]);  s1[3]  = fmaf(qa.w,  kv1, s1[3]);
            s0[4]  = fmaf(qbv.x, kv0, s0[4]);  s1[4]  = fmaf(qbv.x, kv1, s1[4]);
            s0[5]  = fmaf(qbv.y, kv0, s0[5]);  s1[5]  = fmaf(qbv.y, kv1, s1[5]);
            s0[6]  = fmaf(qbv.z, kv0, s0[6]);  s1[6]  = fmaf(qbv.z, kv1, s1[6]);
            s0[7]  = fmaf(qbv.w, kv0, s0[7]);  s1[7]  = fmaf(qbv.w, kv1, s1[7]);
            s0[8]  = fmaf(qc.x,  kv0, s0[8]);  s1[8]  = fmaf(qc.x,  kv1, s1[8]);
            s0[9]  = fmaf(qc.y,  kv0, s0[9]);  s1[9]  = fmaf(qc.y,  kv1, s1[9]);
            s0[10] = fmaf(qc.z,  kv0, s0[10]); s1[10] = fmaf(qc.z,  kv1, s1[10]);
            s0[11] = fmaf(qc.w,  kv0, s0[11]); s1[11] = fmaf(qc.w,  kv1, s1[11]);
            s0[12] = fmaf(qd.x,  kv0, s0[12]); s1[12] = fmaf(qd.x,  kv1, s1[12]);
            s0[13] = fmaf(qd.y,  kv0, s0[13]); s1[13] = fmaf(qd.y,  kv1, s1[13]);
            s0[14] = fmaf(qd.z,  kv0, s0[14]); s1[14] = fmaf(qd.z,  kv1, s1[14]);
            s0[15] = fmaf(qd.w,  kv0, s0[15]); s1[15] = fmaf(qd.w,  kv1, s1[15]);
        }

        // ---- softmax: exact max (order-invariant), cross-wave via LDS ----
#pragma unroll
        for (int j = 0; j < 16; j++) {
            s0[j] *= SCALE; s1[j] *= SCALE;
            float m = fmaxf(s0[j], s1[j]);
            for (int o = 32; o; o >>= 1) m = fmaxf(m, __shfl_xor(m, o));
            if (lane == 0) m_buf[w][j] = m;
        }
        __syncthreads();
#pragma unroll
        for (int jq = 0; jq < 4; jq++) {
            float4 m0 = *(const float4*)&m_buf[0][jq * 4];
            float4 m1 = *(const float4*)&m_buf[1][jq * 4];
            float4 m2 = *(const float4*)&m_buf[2][jq * 4];
            float4 m3 = *(const float4*)&m_buf[3][jq * 4];
            float4 mg;
            mg.x = fmaxf(fmaxf(m0.x, m1.x), fmaxf(m2.x, m3.x));
            mg.y = fmaxf(fmaxf(m0.y, m1.y), fmaxf(m2.y, m3.y));
            mg.z = fmaxf(fmaxf(m0.z, m1.z), fmaxf(m2.z, m3.z));
            mg.w = fmaxf(fmaxf(m0.w, m1.w), fmaxf(m2.w, m3.w));
#pragma unroll
            for (int j2 = 0; j2 < 4; j2++) {
                const int j = jq * 4 + j2;
                const float mgv = (j2 == 0) ? mg.x : (j2 == 1) ? mg.y : (j2 == 2) ? mg.z : mg.w;
                float e0 = expf(s0[j] - mgv);
                float e1 = expf(s1[j] - mgv);
                s0[j] = e0; s1[j] = e1;
                float ls = e0 + e1;
                for (int o = 32; o; o >>= 1) ls += __shfl_xor(ls, o);
                if (lane == 0) l_buf[w][j] = ls;
            }
        }
        __syncthreads();
#pragma unroll
        for (int jq = 0; jq < 4; jq++) {
            float4 l0 = *(const float4*)&l_buf[0][jq * 4];
            float4 l1 = *(const float4*)&l_buf[1][jq * 4];
            float4 l2 = *(const float4*)&l_buf[2][jq * 4];
            float4 l3 = *(const float4*)&l_buf[3][jq * 4];
            float4 lt;
            lt.x = l0.x + l1.x + l2.x + l3.x;
            lt.y = l0.y + l1.y + l2.y + l3.y;
            lt.z = l0.z + l1.z + l2.z + l3.z;
            lt.w = l0.w + l1.w + l2.w + l3.w;
#pragma unroll
            for (int j2 = 0; j2 < 4; j2++) {
                const int j = jq * 4 + j2;
                const float ltv = (j2 == 0) ? lt.x : (j2 == 1) ? lt.y : (j2 == 2) ? lt.z : lt.w;
                const float inv = 1.f / ltv;
                float p0 = s0[j] * inv;
                float p1 = s1[j] * inv;
                p_s[j * 520 + w * 128 + lane]      = f2b(p0);
                p_s[j * 520 + w * 128 + 64 + lane] = f2b(p1);
                bs0 += p0; bs1 += p1;
            }
        }
        // wave's PV reads only its OWN p_s columns -> no barrier needed here

        // ---- PV via MFMA: wave w covers k-range [w*128, w*128+128) ----
        f32x4 acc[3];
#pragma unroll
        for (int nt = 0; nt < 3; nt++) acc[nt] = (f32x4){0.f, 0.f, 0.f, 0.f};
#pragma unroll
        for (int ks = 0; ks < 4; ks++) {
            const int k0 = w * 128 + ks * 32;
            bf16x8 av = *(const bf16x8*)&p_s[lrow * 520 + k0 + lgr * 8];
#pragma unroll
            for (int nt = 0; nt < 3; nt++) {
                bf16x8 bv = *(const bf16x8*)&vf[(((size_t)(w * 4 + ks) * 3 + nt) * 64 + lane) * 8];
                acc[nt] = __builtin_amdgcn_mfma_f32_16x16x32_bf16(av, bv, acc[nt], 0, 0, 0);
            }
        }
        __syncthreads();   // all PV p_s reads done before red overlays p_s

        // ---- cross-wave k-reduction (red overlays p_s) ----
#pragma unroll
        for (int nt = 0; nt < 3; nt++)
#pragma unroll
            for (int r = 0; r < 4; r++)
                red[w * 768 + (nt * 4 + r) * 64 + lane] = acc[nt][r];
        __syncthreads();
        for (int i = tid; i < 16 * 48; i += 256) {
            int q = i / 48, d = i - q * 48;
            if (d < D_) {
                int lg = q >> 2, r = q & 3, nt = d >> 4, lr = d & 15;
                int fi = (nt * 4 + r) * 64 + lg * 16 + lr;
                float v = red[fi] + red[768 + fi] + red[1536 + fi] + red[2304 + fi];
                outp[((size_t)(b * L_ + q0 + q)) * (H_ * D_) + h * D_ + d] = g0_s[q] * v;
            }
        }
        __syncthreads();   // red/q_sT dead before next pass
    }

    // ---- block scores: thread owns keys w*128+lane, +64 exclusively ----
    const int j0 = w * 128 + lane;
    if (bsp) {
        float* bp = &bsp[((size_t)h * QB_ + qb) * LC_];
        bp[j0] = bs0;
        bp[j0 + 64] = bs1;
    } else {
        double* bqd = &bscore[((size_t)(qb & (NREP_ - 1)) * H_ + h) * LC_];
        atomicAdd(&bqd[j0], (double)bs0);
        atomicAdd(&bqd[j0 + 64], (double)bs1);
    }
}

// ================= K4: top-k (per batch; fp32 partials or replicated fp64) ==
// grid 20, block 64
__global__ __launch_bounds__(64) void k_topk(const double* __restrict__ bs,
                                             const float* __restrict__ bsp,
                                             int* __restrict__ idxo)
{
    __shared__ double vb_[64];
    __shared__ int ib_[64];
    __shared__ int win;
    const int h = blockIdx.x, lane = threadIdx.x;
    double vals[8];
    if (bsp) {   // deterministic sequential fp64 sum of the 112 fp32 per-block partials
#pragma unroll
        for (int r = 0; r < 8; r++) vals[r] = 0.0;
        for (int pb = 0; pb < QB_; pb++) {
            const float* rowp = &bsp[((size_t)h * QB_ + pb) * LC_];
#pragma unroll
            for (int r = 0; r < 8; r++) vals[r] += (double)rowp[r * 64 + lane];
        }
    } else {     // sum the NREP_ fp64 replicas
#pragma unroll
        for (int r = 0; r < 8; r++) {
            int j = r * 64 + lane;
            double v = 0.0;
#pragma unroll
            for (int rep = 0; rep < NREP_; rep++)
                v += bs[((size_t)rep * H_ + h) * LC_ + j];
            vals[r] = v;
        }
    }
    for (int t = 0; t < TOPK_; t++) {
        double bv = -1e30; int bi = 0x7fffffff;
#pragma unroll
        for (int r = 0; r < 8; r++) {
            int j = r * 64 + lane;
            bool better = (vals[r] > bv) || (vals[r] == bv && j < bi);
            if (better) { bv = vals[r]; bi = j; }
        }
        vb_[lane] = bv; ib_[lane] = bi;
        __syncthreads();
        if (lane == 0) {
            double best = -1e30; int besti = 0x7fffffff;
            for (int u = 0; u < 64; u++) {
                if (vb_[u] > best || (vb_[u] == best && ib_[u] < besti)) { best = vb_[u]; besti = ib_[u]; }
            }
            idxo[h * TOPK_ + t] = besti;
            win = besti;
        }
        __syncthreads();
        int w = win;
#pragma unroll
        for (int r = 0; r < 8; r++)
            if ((w >> 6) == r && (w & 63) == lane) vals[r] = -1e30;
        __syncthreads();
    }
}

// ================= K5 v3: selected + window attention, 32 queries/block ==============
// grid (QB_, 20), block 256. Wave owns 8 queries in 2 groups of 4.
__global__ __launch_bounds__(256) void k_selwin(
    const float* __restrict__ q32, const bfu* __restrict__ k16,
    const float* __restrict__ v32, const int* __restrict__ idxp,
    const float* __restrict__ wg, const float* __restrict__ bg,
    float* __restrict__ outp, int b)
{
    __shared__ __align__(16) bfu ks_s[119][44];      // 112 sel + 7 window keys
    __shared__ __align__(16) float vsT[D_][130];     // fp32 v^T, pad 130
    __shared__ __align__(16) float q_s[32][44];
    __shared__ __align__(16) bfu p_s[32][NSEL_];
    __shared__ int rows_s[NSEL_];
    __shared__ float g1_s[32];
    __shared__ float pw_s[32][CB_];                  // g2-scaled window probs
    const int h = blockIdx.y;
    const int q0 = blockIdx.x * 32;
    const int tid = threadIdx.x, lane = tid & 63, wave = tid >> 6;
    const size_t kvbase = (size_t)h * L_ * D_;

    for (int i = tid; i < 32 * D_; i += 256) {
        int qq = i / D_, d = i - qq * D_;
        q_s[qq][d] = q32[((size_t)h * L_ + q0 + qq) * D_ + d];
    }
    if (tid < NSEL_) {
        int t = tid / CB_;
        rows_s[tid] = idxp[h * TOPK_ + t] * CB_ + (tid - t * CB_);
    }
    __syncthreads();

    for (int i = tid; i < 119 * D_; i += 256) {
        int key = i / D_, d = i - key * D_;
        int row = (key < NSEL_) ? rows_s[key] : (L_ - CB_ + (key - NSEL_));
        ks_s[key][d] = k16[kvbase + (size_t)row * D_ + d];
        vsT[d][key]  = v32[kvbase + (size_t)row * D_ + d];
    }
    __syncthreads();

    if (tid < 32) {   // gates + window softmax (x g2)
        float a0 = bg[0], a1 = bg[1], a2 = bg[2];
        for (int d = 0; d < D_; d++) {
            float qd = q_s[tid][d];
            a0 += qd * wg[d * 3 + 0];
            a1 += qd * wg[d * 3 + 1];
            a2 += qd * wg[d * 3 + 2];
        }
        float gm = fmaxf(a0, fmaxf(a1, a2));
        float e0 = __expf(a0 - gm), e1 = __expf(a1 - gm), e2 = __expf(a2 - gm);
        float ginv = 1.f / (e0 + e1 + e2);
        g1_s[tid] = e1 * ginv;
        float g2 = e2 * ginv;
        float sw[CB_];
        float m = -1e30f;
        for (int i = 0; i < CB_; i++) {
            float ss = 0.f;
            for (int d = 0; d < D_; d++) ss += q_s[tid][d] * b2f(ks_s[NSEL_ + i][d]);
            sw[i] = ss * SCALE;
            m = fmaxf(m, sw[i]);
        }
        float lsum = 0.f;
        for (int i = 0; i < CB_; i++) { sw[i] = __expf(sw[i] - m); lsum += sw[i]; }
        float winv = g2 / lsum;
        for (int i = 0; i < CB_; i++) pw_s[tid][i] = sw[i] * winv;
    }
    __syncthreads();

    const bool v1 = (64 + lane) < NSEL_;
    const int row1c = v1 ? (64 + lane) : 0;
    for (int g = 0; g < 2; g++) {
        const int qb2 = wave * 8 + g * 4;
        float s0[4] = {0, 0, 0, 0}, s1[4] = {0, 0, 0, 0};
        for (int dc = 0; dc < 10; dc++) {
            float4 qv[4];
#pragma unroll
            for (int qi = 0; qi < 4; qi++) qv[qi] = *(const float4*)&q_s[qb2 + qi][dc * 4];
            uint2 ra = *(const uint2*)&ks_s[lane][dc * 4];
            uint2 rb = *(const uint2*)&ks_s[row1c][dc * 4];
            float a0, a1, a2, a3, c0, c1, c2, c3;
            b2x2(ra.x, a0, a1); b2x2(ra.y, a2, a3);
            b2x2(rb.x, c0, c1); b2x2(rb.y, c2, c3);
#pragma unroll
            for (int qi = 0; qi < 4; qi++) {
                s0[qi] += qv[qi].x * a0 + qv[qi].y * a1 + qv[qi].z * a2 + qv[qi].w * a3;
                s1[qi] += qv[qi].x * c0 + qv[qi].y * c1 + qv[qi].z * c2 + qv[qi].w * c3;
            }
        }
        {
            float ka = b2f(ks_s[lane][40]);
            float kb = b2f(ks_s[row1c][40]);
#pragma unroll
            for (int qi = 0; qi < 4; qi++) {
                float qt = q_s[qb2 + qi][40];
                s0[qi] += qt * ka; s1[qi] += qt * kb;
            }
        }
#pragma unroll
        for (int qi = 0; qi < 4; qi++) {
            float a0 = s0[qi] * SCALE;
            float a1 = v1 ? s1[qi] * SCALE : -1e30f;
            float m = fmaxf(a0, a1);
            for (int o = 32; o; o >>= 1) m = fmaxf(m, __shfl_xor(m, o));
            float e0 = __expf(a0 - m);
            float e1 = v1 ? __expf(a1 - m) : 0.f;
            float lsum = e0 + e1;
            for (int o = 32; o; o >>= 1) lsum += __shfl_xor(lsum, o);
            float inv = 1.f / lsum;
            p_s[qb2 + qi][lane] = f2b(e0 * inv);
            if (v1) p_s[qb2 + qi][64 + lane] = f2b(e1 * inv);
        }
    }
    __syncthreads();

    if (lane < D_) {
        for (int g = 0; g < 2; g++) {
            const int qb2 = wave * 8 + g * 4;
            float acc[4] = {0, 0, 0, 0};
            for (int jc = 0; jc < NSEL_; jc += 4) {
                float2 va = *(const float2*)&vsT[lane][jc];
                float2 vb = *(const float2*)&vsT[lane][jc + 2];
#pragma unroll
                for (int qi = 0; qi < 4; qi++) {
                    uint2 pp = *(const uint2*)&p_s[qb2 + qi][jc];
                    float p0, p1, p2, p3;
                    b2x2(pp.x, p0, p1); b2x2(pp.y, p2, p3);
                    acc[qi] += p0 * va.x + p1 * va.y + p2 * vb.x + p3 * vb.y;
                }
            }
#pragma unroll
            for (int qi = 0; qi < 4; qi++) {
                int row = qb2 + qi;
                float wvv = 0.f;
#pragma unroll
                for (int i = 0; i < CB_; i++) wvv += pw_s[row][i] * vsT[lane][NSEL_ + i];
                float* op = &outp[((size_t)(b * L_ + q0 + row)) * (H_ * D_) + h * D_ + lane];
                *op = *op + g1_s[row] * acc[qi] + wvv;
            }
        }
    }
}

extern "C" void kernel_launch(void* const* d_in, const int* in_sizes, int n_in,
                              void* d_out, int out_size, void* d_ws, size_t ws_size,
                              hipStream_t stream) {
    (void)in_sizes; (void)n_in;
    const float* x  = (const float*)d_in[0];
    const float* wq = (const float*)d_in[1];  const float* bq = (const float*)d_in[2];
    const float* wk = (const float*)d_in[3];  const float* bk = (const float*)d_in[4];
    const float* wv = (const float*)d_in[5];  const float* bv = (const float*)d_in[6];
    const float* w1 = (const float*)d_in[7];  const float* b1 = (const float*)d_in[8];
    const float* w2 = (const float*)d_in[9];  const float* b2 = (const float*)d_in[10];
    const float* wg = (const float*)d_in[11]; const float* bg = (const float*)d_in[12];

    if (d_ws == nullptr || ws_size < WS_NEEDED) {
        k_fail<<<dim3((out_size + 255) / 256), 256, 0, stream>>>((float*)d_out, out_size);
        return;
    }

    char* ws = (char*)d_ws;
    float*  r1   = (float*)(ws + OFF_R1);    // k32 then q32
    float*  v32  = (float*)(ws + OFF_V32);
    bfu*    k16  = (bfu*)(ws + OFF_K16);
    float*  kcT  = (float*)(ws + OFF_KCT);
    bfu*    vcF  = (bfu*)(ws + OFF_VCF);
    double* bsc  = (double*)(ws + OFF_BS);
    int*    idxp = (int*)(ws + OFF_IDX);
    float*  outp = (float*)d_out;
    // atomic-free block-score partials if workspace allows (else replicated fp64 atomics)
    const bool big = (ws_size >= WS_BIG);
    float*  bsp  = big ? (float*)(ws + OFF_BSP) : (float*)nullptr;

    for (int b = 0; b < B_; b++) {
        if (!big)
            k_zero_d<<<dim3((NREP_ * H_ * LC_ + 255) / 256), 256, 0, stream>>>(bsc, NREP_ * H_ * LC_);
        // K -> r1 and V -> v32 in one fused launch
        k_proj2<<<dim3(L_ / 8, 2, 2), 256, 0, stream>>>(x, wk, bk, r1, wv, bv, v32, b);
        // fused compression MLP: y=0 K path (kcT + k16 from r1), y=1 V path (vcF from v32)
        k_cmlp<<<dim3(H_ * LC_ / 4, 2), 256, 0, stream>>>(r1, v32, w1, b1, w2, b2, kcT, k16, vcF);
        // Q -> r1 (overwrites k32; cmlp K path done)
        k_proj2<<<dim3(L_ / 8, 2, 1), 256, 0, stream>>>(x, wq, bq, r1, wq, bq, r1, b);
        k_comp<<<dim3(QB_, H_), 256, 0, stream>>>(r1, kcT, vcF, wg, bg, outp, bsc, bsp, b);
        k_topk<<<dim3(H_), 64, 0, stream>>>(bsc, bsp, idxp);
        k_selwin<<<dim3(QB_, H_), 256, 0, stream>>>(r1, k16, v32, idxp, wg, bg, outp, b);
    }
}